// Round 5
// baseline (1248.561 us; speedup 1.0000x reference)
//
#include <hip/hip_runtime.h>
#include <math.h>
#include <float.h>

// Problem constants: B=4, N=3136, C=64, C2=128, H=W=56, stride2 -> 28x28,
// Ns = ceil(N*0.25) = 784, k = 5.  Inputs are float32/int32 per reference.
#define Bq   4
#define Nq   3136
#define Cq   64
#define C2q  128
#define Hq   56
#define Wq   56
#define HWq  (Hq*Wq)
#define HOq  28
#define WOq  28
#define HWOq (HOq*WOq)
#define NSq  784
#define KNN  5
#define BNq  (Bq*Nq)

#define T64   64             // i/j tile for distance kernels
#define KC    32             // K chunk
#define NIT64 (Nq/T64)       // 49 i-tiles (exact)
#define NPAIR (NIT64*(NIT64+1)/2)  // 1225 lower-tri tile pairs
#define NSPL  8              // j-range splits (grid 1568)
#define NSPA  2              // assign center-range splits
#define LDP   34             // LDS row stride (even -> 16B-aligned double2)

__device__ __constant__ int c_spl[NSPL + 1]  = {0, 7, 13, 19, 25, 31, 37, 43, 49};
__device__ __constant__ int c_spla[NSPA + 1] = {0, 7, 13};

typedef unsigned int   u32;
typedef unsigned long long u64;
typedef __attribute__((ext_vector_type(4))) double d64x4;

static __device__ __forceinline__ void atomicMaxPosD(double* p, double v) {
    atomicMax((u64*)p, (u64)__double_as_longlong(v));
}
static __device__ __forceinline__ int clampTok(int t) {
    return min(max(t, 0), Nq - 1);
}

// sorted-ascending insert into 5-list (static indices after unroll)
static __device__ __forceinline__ void ins5(double* a, double v) {
    if (v < a[KNN - 1]) {
        a[KNN - 1] = v;
        #pragma unroll
        for (int m = KNN - 1; m > 0; m--)
            if (a[m] < a[m - 1]) { double t = a[m]; a[m] = a[m - 1]; a[m - 1] = t; }
    }
}
static __device__ __forceinline__ void cex(double& a, double& b) {
    double lo = fmin(a, b), hi = fmax(a, b); a = lo; b = hi;
}
// merge two ascending 5-lists, keep 5 smallest ascending.  STATIC INDICES ONLY.
static __device__ __forceinline__ void merge5(double* a, const double* p) {
    double t0 = fmin(a[0], p[4]);
    double t1 = fmin(a[1], p[3]);
    double t2 = fmin(a[2], p[2]);
    double t3 = fmin(a[3], p[1]);
    double t4 = fmin(a[4], p[0]);
    cex(t0, t1); cex(t1, t2); cex(t2, t3); cex(t3, t4);
    cex(t0, t1); cex(t1, t2); cex(t2, t3);
    cex(t0, t1); cex(t1, t2);
    cex(t0, t1);
    a[0] = t0; a[1] = t1; a[2] = t2; a[3] = t3; a[4] = t4;
}

// ---------------------------------------------------------------------------
// f64 MFMA layout probe (validated on HW in R2-R4: mode 0/1 path taken).
// ---------------------------------------------------------------------------
static __device__ __forceinline__ int mfma_mode_probe(int l4, int l15) {
    d64x4 p;
    #pragma unroll
    for (int v = 0; v < 4; v++) p[v] = 0.0;
    double a1 = (l4 == 0) ? (double)(16 * l15) : 0.0;
    double b1 = (l4 == 0) ? 1.0 : 0.0;
    p = __builtin_amdgcn_mfma_f64_16x16x4f64(a1, b1, p, 0, 0, 0);   // D += 16*m
    double a2 = (l4 == 0) ? 1.0 : 0.0;
    double b2 = (l4 == 0) ? (double)l15 : 0.0;
    p = __builtin_amdgcn_mfma_f64_16x16x4f64(a2, b2, p, 0, 0, 0);   // D += n
    bool ok0 = true, ok1 = true;
    #pragma unroll
    for (int v = 0; v < 4; v++) {
        ok0 = ok0 && (p[v] == (double)(16 * (4 * l4 + v) + l15));
        ok1 = ok1 && (p[v] == (double)(16 * (l4 + 4 * v) + l15));
    }
    return __all(ok0) ? 0 : (__all(ok1) ? 1 : 2);
}

// ---- jax threefry2x32 noise: uniform(key(42), (4,3136)) -------------------
static __device__ __forceinline__ u32 rotl32(u32 x, int d) { return (x << d) | (x >> (32 - d)); }
static __device__ __forceinline__ float tf_uniform(int t) {
    const u32 k0 = 0u, k1 = 42u;
    const u32 ks2 = k0 ^ k1 ^ 0x1BD11BDAu;
    u32 ks[3] = { k0, k1, ks2 };
    bool lo = (t < 6272);
    u32 cx0 = lo ? (u32)t : (u32)(t - 6272);
    u32 cx1 = lo ? (u32)(t + 6272) : (u32)t;
    u32 x0 = cx0 + ks[0];
    u32 x1 = cx1 + ks[1];
    const int R0[4] = {13, 15, 26, 6};
    const int R1[4] = {17, 29, 16, 24};
    #pragma unroll
    for (int i = 0; i < 5; i++) {
        const int* rot = (i % 2 == 0) ? R0 : R1;
        #pragma unroll
        for (int r = 0; r < 4; r++) { x0 += x1; x1 = rotl32(x1, rot[r]); x1 ^= x0; }
        x0 += ks[(i + 1) % 3];
        x1 += ks[(i + 2) % 3] + (u32)(i + 1);
    }
    u32 bits = lo ? x0 : x1;
    u32 fb = (bits >> 9) | 0x3f800000u;
    float f; __builtin_memcpy(&f, &fb, 4);
    return f - 1.0f;
}

// ---- grid index: clip(loc,-1,1)*0.5+0.5 -> round-half-even ----------------
static __device__ __forceinline__ int gridIndex(float lx, float ly, int Wd, int Hd) {
    double x = fmin(fmax((double)lx, -1.0), 1.0) * 0.5 + 0.5;
    double y = fmin(fmax((double)ly, -1.0), 1.0) * 0.5 + 0.5;
    int ix = (int)rint(x * (double)(Wd - 1)); ix = min(max(ix, 0), Wd - 1);
    int iy = (int)rint(y * (double)(Hd - 1)); iy = min(max(iy, 0), Hd - 1);
    return iy * Wd + ix;
}

// ---------------------------------------------------------------------------
__global__ void ctm_fallback(float* out, int n) {
    int t = blockIdx.x * blockDim.x + threadIdx.x;
    if (t < n) out[t] = 0.0f;
}

__global__ void ctm_prep(const float* __restrict__ loc, const int* __restrict__ idx_agg,
                         const float* __restrict__ aggw,
                         int* cell56, int* cell28, int* cnt56, double* allwtok) {
    int t = blockIdx.x * blockDim.x + threadIdx.x;
    if (t >= BNq) return;
    int b = t / Nq;
    float lx = loc[2 * t], ly = loc[2 * t + 1];
    int c56 = gridIndex(lx, ly, Wq, Hq);
    int c28 = gridIndex(lx, ly, WOq, HOq);
    cell56[t] = c56; cell28[t] = c28;
    atomicAdd(&cnt56[b * HWq + c56], 1);
    int tok = clampTok(idx_agg[t]);
    atomicAdd(&allwtok[b * Nq + tok], (double)aggw[t]);
}

// t2m, (point,channel)-parallel: one coalesced f64 atomic per thread.
__global__ void ctm_t2m(const float* __restrict__ x, const int* __restrict__ idx_agg,
                        const int* __restrict__ cell56, const int* __restrict__ cnt56,
                        double* xmap56T) {
    int id = blockIdx.x * blockDim.x + threadIdx.x;
    if (id >= BNq * Cq) return;
    int t = id / Cq, c = id - t * Cq;
    int b = t / Nq;
    int cell = cell56[t];
    double v = 1.0 / ((double)cnt56[b * HWq + cell] + 1e-6);
    double xv = (double)x[(size_t)(b * Nq + clampTok(idx_agg[t])) * Cq + c];
    atomicAdd(&xmap56T[((size_t)b * HWq + cell) * Cq + c], xv * v);
}

// one-time weight transpose: wT[(ci*9+tap)*C2q+co] = w[co*Cq*9 + ci*9 + tap]
__global__ void ctm_wt(const float* __restrict__ w, float* wT) {
    int id = blockIdx.x * blockDim.x + threadIdx.x;
    if (id >= C2q * Cq * 9) return;
    int co = id & (C2q - 1);
    int rem = id >> 7;
    int tap = rem % 9;
    int ci = rem / 9;
    wT[id] = w[(size_t)co * Cq * 9 + ci * 9 + tap];
}

// conv 3x3 stride2: block = 2 cells x 128 co, input taps staged in LDS.
__global__ __launch_bounds__(256)
void ctm_conv(const double* __restrict__ xmap56T, const float* __restrict__ wT,
              const float* __restrict__ bias, double* xmap28T) {
    __shared__ double sIn[2][9][Cq];
    int blk = blockIdx.x;
    int b  = blk & (Bq - 1);
    int cp = blk >> 2;              // cell pair index, 0..391
    int tid = threadIdx.x;
    int co = tid & (C2q - 1);
    int cl = tid >> 7;              // 0 or 1
    const double* xb = xmap56T + (size_t)b * HWq * Cq;
    for (int idx = tid; idx < 2 * 9 * Cq; idx += 256) {
        int cell_l = idx / (9 * Cq);
        int rem = idx - cell_l * (9 * Cq);
        int tap = rem >> 6;
        int ci  = rem & 63;
        int cell = 2 * cp + cell_l;
        int ox = cell % WOq, oy = cell / WOq;
        int ky = tap / 3, kx = tap - ky * 3;
        int iy = 2 * oy + ky - 1, ix = 2 * ox + kx - 1;
        double v = 0.0;
        if (iy >= 0 && iy < Hq && ix >= 0 && ix < Wq)
            v = xb[(size_t)(iy * Wq + ix) * Cq + ci];
        sIn[cell_l][tap][ci] = v;
    }
    __syncthreads();
    double acc = (double)bias[co];
    for (int ci = 0; ci < Cq; ci++) {
        #pragma unroll
        for (int tap = 0; tap < 9; tap++)
            acc += sIn[cl][tap][ci] * (double)wT[(size_t)(ci * 9 + tap) * C2q + co];
    }
    int cell = 2 * cp + cl;
    xmap28T[((size_t)b * HWOq + cell) * C2q + co] = acc;
}

// m2t, (point,channel)-parallel: coalesced.
__global__ void ctm_m2t(const double* __restrict__ xmap28T, const float* __restrict__ aggw,
                        const int* __restrict__ idx_agg, const int* __restrict__ cell28,
                        const double* __restrict__ allwtok, double* xt) {
    int id = blockIdx.x * blockDim.x + threadIdx.x;
    if (id >= BNq * C2q) return;
    int t = id / C2q, c = id - t * C2q;
    int b = t / Nq;
    int tok = clampTok(idx_agg[t]);
    double v = (double)aggw[t] / (allwtok[b * Nq + tok] + 1e-6);
    double f = xmap28T[((size_t)b * HWOq + cell28[t]) * C2q + c];
    atomicAdd(&xt[(size_t)(b * Nq + tok) * C2q + c], f * v);
}

// finalize v2: wave-shuffle reductions (4 barriers, was 28).
__global__ __launch_bounds__(C2q)
void ctm_finalize(double* xt, const float* __restrict__ x, const float* __restrict__ skipw,
                  const float* __restrict__ lng, const float* __restrict__ lnb,
                  const float* __restrict__ confw, const float* __restrict__ confb,
                  double* x2o, double* weightv) {
    int bn = blockIdx.x; int c = threadIdx.x;
    int lane = c & 63, w = c >> 6;
    double* row = xt + (size_t)bn * C2q;
    const float* xr = x + (size_t)bn * Cq;
    double acc = row[c];
    const float* sw = skipw + c * Cq;
    #pragma unroll 16
    for (int k = 0; k < Cq; k++) acc += (double)xr[k] * (double)sw[k];
    __shared__ double slot[4][2];
    double s = acc;
    #pragma unroll
    for (int m = 1; m <= 32; m <<= 1) s += __shfl_xor(s, m);
    if (lane == 0) slot[0][w] = s;
    __syncthreads();
    double mu = (slot[0][0] + slot[0][1]) * (1.0 / C2q);
    double d = acc - mu;
    s = d * d;
    #pragma unroll
    for (int m = 1; m <= 32; m <<= 1) s += __shfl_xor(s, m);
    if (lane == 0) slot[1][w] = s;
    __syncthreads();
    double var = (slot[1][0] + slot[1][1]) * (1.0 / C2q);
    double v = d / sqrt(var + 1e-5) * (double)lng[c] + (double)lnb[c];
    row[c] = v;
    s = v * v;
    #pragma unroll
    for (int m = 1; m <= 32; m <<= 1) s += __shfl_xor(s, m);
    if (lane == 0) slot[2][w] = s;
    double s2 = v * (double)confw[c];
    #pragma unroll
    for (int m = 1; m <= 32; m <<= 1) s2 += __shfl_xor(s2, m);
    if (lane == 0) slot[3][w] = s2;
    __syncthreads();
    if (c == 0) {
        x2o[bn] = slot[2][0] + slot[2][1];
        weightv[bn] = exp(slot[3][0] + slot[3][1] + (double)confb[0]);
    }
}

// ---------------------------------------------------------------------------
// Distance kernels v6.0: pass2 rewritten as density-sorted LOWER-TRIANGULAR
// tile sweep (ctm_sortd + ctm_perm + ctm_pass2t + ctm_merge2t): the masked
// min over {j: density_j > density_i} is exactly a min over PREDECESSORS in
// density-descending rank order -> 51% of the tiles, one tile-pair per block
// (4900 blocks).  BITWISE exact vs the recompute path: identical MFMA
// k-chains on identical data, fmin over the same set.  Old recompute pass2
// retained as a ws/mode fallback tier.  pass1/assign unchanged from R3.
// ---------------------------------------------------------------------------

// pass1: per row i -> 5 smallest d2 + row max d2 (partial per j-split)
__global__ __launch_bounds__(256, 2)
void ctm_pass1(const double* __restrict__ xt, const double* __restrict__ x2,
               double* pbest, double* pmax) {
    __shared__ double sBB[2][T64][LDP];
    __shared__ double sx2j[2][T64];
    int blk = blockIdx.x;
    int b  = blk & (Bq - 1);
    int s  = (blk >> 2) & (NSPL - 1);
    int it = blk >> 5;
    int tid = threadIdx.x;
    const double* xtb = xt + (size_t)b * Nq * C2q;
    const double* x2b = x2 + (size_t)b * Nq;
    int i0 = it * T64;
    int jt_beg = c_spl[s], jt_end = c_spl[s + 1];

    int wv = tid >> 6, ln = tid & 63;
    int l15 = ln & 15, l4 = ln >> 4;
    int mode = mfma_mode_probe(l4, l15);

    if (mode < 2) {
        int rw[4];
        #pragma unroll
        for (int v = 0; v < 4; v++) rw[v] = (mode == 0) ? (4 * l4 + v) : (l4 + 4 * v);
        int rbase = i0 + wv * 16;
        double a_reg[4][8];
        const double* arow = xtb + (size_t)(i0 + wv * 16 + l15) * C2q + l4;
        #pragma unroll
        for (int kc = 0; kc < 4; kc++)
            #pragma unroll
            for (int st = 0; st < 8; st++)
                a_reg[kc][st] = arow[kc * KC + 4 * st];
        double x2i[4];
        #pragma unroll
        for (int v = 0; v < 4; v++) x2i[v] = x2b[rbase + rw[v]];
        double best[4][KNN]; double mx[4];
        #pragma unroll
        for (int v = 0; v < 4; v++) {
            mx[v] = -DBL_MAX;
            #pragma unroll
            for (int k = 0; k < KNN; k++) best[v][k] = DBL_MAX;
        }
        {
            int j0 = jt_beg * T64;
            #pragma unroll
            for (int w = 0; w < 4; w++) {
                int idx = tid + w * 256; int r = idx >> 4, c = (idx & 15) * 2;
                *(double2*)&sBB[0][r][c] = *(const double2*)&xtb[(size_t)(j0 + r) * C2q + c];
            }
            if (tid < T64) sx2j[0][tid] = x2b[j0 + tid];
        }
        __syncthreads();
        int q = 0;
        for (int jt = jt_beg; jt < jt_end; jt++) {
            int j0 = jt * T64;
            d64x4 acc[4];
            #pragma unroll
            for (int bc = 0; bc < 4; bc++)
                #pragma unroll
                for (int v = 0; v < 4; v++) acc[bc][v] = 0.0;
            #pragma unroll
            for (int kc = 0; kc < 4; kc++) {
                const int cb = kc & 1, nb = cb ^ 1, nkc = (kc + 1) & 3;
                const bool lastk = (kc == 3);
                bool hn = !lastk || (jt + 1 < jt_end);
                int nj0 = lastk ? j0 + T64 : j0;
                double2 sreg[4]; double xr = 0.0;
                if (hn) {
                    #pragma unroll
                    for (int w = 0; w < 4; w++) {
                        int idx = tid + w * 256; int r = idx >> 4, c = (idx & 15) * 2;
                        sreg[w] = *(const double2*)&xtb[(size_t)(nj0 + r) * C2q + nkc * KC + c];
                    }
                    if (lastk && tid < T64) xr = x2b[nj0 + tid];
                }
                #pragma unroll
                for (int st = 0; st < 8; st++) {
                    double av = a_reg[kc][st];
                    #pragma unroll
                    for (int bc = 0; bc < 4; bc++) {
                        double bv = sBB[cb][bc * 16 + l15][4 * st + l4];
                        acc[bc] = __builtin_amdgcn_mfma_f64_16x16x4f64(av, bv, acc[bc], 0, 0, 0);
                    }
                }
                if (hn) {
                    #pragma unroll
                    for (int w = 0; w < 4; w++) {
                        int idx = tid + w * 256; int r = idx >> 4, c = (idx & 15) * 2;
                        *(double2*)&sBB[nb][r][c] = sreg[w];
                    }
                    if (lastk && tid < T64) sx2j[q ^ 1][tid] = xr;
                }
                __syncthreads();
            }
            #pragma unroll
            for (int bc = 0; bc < 4; bc++) {
                double xj = sx2j[q][bc * 16 + l15];
                #pragma unroll
                for (int v = 0; v < 4; v++) {
                    double d2 = x2i[v] + xj - 2.0 * acc[bc][v];
                    mx[v] = fmax(mx[v], d2);
                    ins5(best[v], d2);
                }
            }
            q ^= 1;
        }
        for (int m = 1; m <= 8; m <<= 1) {
            #pragma unroll
            for (int v = 0; v < 4; v++) {
                double p[KNN];
                #pragma unroll
                for (int k = 0; k < KNN; k++) p[k] = __shfl_xor(best[v][k], m);
                mx[v] = fmax(mx[v], __shfl_xor(mx[v], m));
                merge5(best[v], p);
            }
        }
        if (l15 == 0) {
            #pragma unroll
            for (int v = 0; v < 4; v++) {
                int gi = b * Nq + rbase + rw[v];
                size_t base = ((size_t)s * BNq + gi) * KNN;
                #pragma unroll
                for (int k = 0; k < KNN; k++) pbest[base + k] = best[v][k];
                pmax[(size_t)s * BNq + gi] = mx[v];
            }
        }
    } else {
        // ---------------- VALU fallback (v2.7 verbatim; sBB aliased) -------
        double (*sA)[LDP] = sBB[0];
        double (*sB)[LDP] = sBB[1];
        int tx = tid & 15, ty = tid >> 4;
        double x2i[4];
        #pragma unroll
        for (int r = 0; r < 4; r++) x2i[r] = x2b[i0 + ty + 16 * r];
        double best[4][KNN]; double mx[4];
        #pragma unroll
        for (int r = 0; r < 4; r++) {
            mx[r] = -DBL_MAX;
            #pragma unroll
            for (int k = 0; k < KNN; k++) best[r][k] = DBL_MAX;
        }
        for (int jt = jt_beg; jt < jt_end; jt++) {
            int j0 = jt * T64;
            double acc[4][4];
            #pragma unroll
            for (int r = 0; r < 4; r++)
                #pragma unroll
                for (int q = 0; q < 4; q++) acc[r][q] = 0.0;
            for (int kc = 0; kc < 4; kc++) {
                __syncthreads();
                #pragma unroll
                for (int idx = tid; idx < T64 * KC / 2; idx += 256) {
                    int r = idx >> 4, c = (idx & 15) * 2;
                    *(double2*)&sA[r][c] = *(const double2*)&xtb[(size_t)(i0 + r) * C2q + kc * KC + c];
                    *(double2*)&sB[r][c] = *(const double2*)&xtb[(size_t)(j0 + r) * C2q + kc * KC + c];
                }
                if (kc == 0 && tid < T64) sx2j[0][tid] = x2b[j0 + tid];
                __syncthreads();
                #pragma unroll 4
                for (int cc = 0; cc < KC; cc += 2) {
                    double2 xi[4], xj[4];
                    #pragma unroll
                    for (int r = 0; r < 4; r++) xi[r] = *(const double2*)&sA[ty + 16 * r][cc];
                    #pragma unroll
                    for (int q = 0; q < 4; q++) xj[q] = *(const double2*)&sB[tx + 16 * q][cc];
                    #pragma unroll
                    for (int r = 0; r < 4; r++)
                        #pragma unroll
                        for (int q = 0; q < 4; q++) acc[r][q] += xi[r].x * xj[q].x;
                    #pragma unroll
                    for (int r = 0; r < 4; r++)
                        #pragma unroll
                        for (int q = 0; q < 4; q++) acc[r][q] += xi[r].y * xj[q].y;
                }
            }
            #pragma unroll
            for (int r = 0; r < 4; r++)
                #pragma unroll
                for (int q = 0; q < 4; q++) {
                    double d2 = x2i[r] + sx2j[0][tx + 16 * q] - 2.0 * acc[r][q];
                    mx[r] = fmax(mx[r], d2);
                    ins5(best[r], d2);
                }
        }
        for (int m = 1; m <= 8; m <<= 1) {
            #pragma unroll
            for (int r = 0; r < 4; r++) {
                double p[KNN];
                #pragma unroll
                for (int k = 0; k < KNN; k++) p[k] = __shfl_xor(best[r][k], m);
                mx[r] = fmax(mx[r], __shfl_xor(mx[r], m));
                merge5(best[r], p);
            }
        }
        if (tx == 0) {
            #pragma unroll
            for (int r = 0; r < 4; r++) {
                int gi = b * Nq + i0 + ty + 16 * r;
                size_t base = ((size_t)s * BNq + gi) * KNN;
                #pragma unroll
                for (int k = 0; k < KNN; k++) pbest[base + k] = best[r][k];
                pmax[(size_t)s * BNq + gi] = mx[r];
            }
        }
    }
}

// merge pass1 partials -> density; fold per-batch max into maxd2 via atomic.
__global__ void ctm_merge1(const double* __restrict__ pbest, const double* __restrict__ pmax,
                           double* density, double* maxd2) {
    int t = blockIdx.x * blockDim.x + threadIdx.x;
    if (t >= BNq) return;
    double a[KNN];
    #pragma unroll
    for (int k = 0; k < KNN; k++) a[k] = pbest[(size_t)t * KNN + k];
    double mxv = pmax[t];
    #pragma unroll
    for (int s = 1; s < NSPL; s++) {
        double p[KNN];
        #pragma unroll
        for (int k = 0; k < KNN; k++) p[k] = pbest[((size_t)s * BNq + t) * KNN + k];
        merge5(a, p);
        mxv = fmax(mxv, pmax[(size_t)s * BNq + t]);
    }
    double sum = 0.0;
    #pragma unroll
    for (int k = 0; k < KNN; k++) sum += fmax(a[k], 0.0);
    density[t] = exp(-sum / (double)(C2q * KNN)) + (double)(tf_uniform(t) * 1e-6f);
    atomicMaxPosD(&maxd2[t / Nq], mxv);
}

// sort by density desc (idx asc ties) -> full rank permutation per batch.
__global__ __launch_bounds__(1024)
void ctm_sortd(const double* __restrict__ density, int* perm) {
    __shared__ double s[4096];
    __shared__ int   si[4096];
    int b = blockIdx.x, tid = threadIdx.x;
    for (int i = tid; i < 4096; i += 1024) {
        if (i < Nq) {
            double v = density[b * Nq + i];
            s[i] = isnan(v) ? -DBL_MAX : v;
            si[i] = i;
        } else { s[i] = -DBL_MAX; si[i] = 0x7fffffff; }
    }
    __syncthreads();
    for (int k = 2; k <= 4096; k <<= 1) {
        for (int j = k >> 1; j > 0; j >>= 1) {
            for (int i = tid; i < 4096; i += 1024) {
                int ixj = i ^ j;
                if (ixj > i) {
                    double s1 = s[i], s2 = s[ixj];
                    int i1 = si[i], i2 = si[ixj];
                    bool before_ij = (s1 > s2) || (s1 == s2 && i1 < i2);
                    bool before_ji = (s2 > s1) || (s2 == s1 && i2 < i1);
                    bool doswap = ((i & k) == 0) ? before_ji : before_ij;
                    if (doswap) { s[i] = s2; s[ixj] = s1; si[i] = i2; si[ixj] = i1; }
                }
            }
            __syncthreads();
        }
    }
    for (int t = tid; t < Nq; t += 1024) {
        int v = si[t];
        perm[b * Nq + t] = ((unsigned)v < (unsigned)Nq) ? v : 0;
    }
}

// permute xt and x2 into rank order: xtp[rank] = xt[perm[rank]]
__global__ void ctm_perm(const double* __restrict__ xt, const double* __restrict__ x2,
                         const int* __restrict__ perm, double* xtp, double* x2p) {
    int id = blockIdx.x * blockDim.x + threadIdx.x;
    if (id >= BNq * C2q) return;
    int t = id / C2q, c = id - t * C2q;
    int b = t / Nq;
    int p = perm[t];
    int src = b * Nq + p;
    xtp[(size_t)t * C2q + c] = xt[(size_t)src * C2q + c];
    if (c == 0) x2p[t] = x2[src];
}

// pass2 TRIANGULAR: one lower-tri tile-pair (it,jt<=it) per block, in rank
// space.  Row r's masked min = min over predecessor cols (c < r).
__global__ __launch_bounds__(256, 2)
void ctm_pass2t(const double* __restrict__ xtp, const double* __restrict__ x2p,
                double* pminP) {
    __shared__ double sBB[2][T64][LDP];
    __shared__ double sx2j[T64];
    __shared__ double sp[4][T64];
    int blk = blockIdx.x;
    int b = blk & (Bq - 1);
    int p = blk >> 2;                 // 0..NPAIR-1
    int it = (int)((sqrt(8.0 * (double)p + 1.0) - 1.0) * 0.5);
    while ((it + 1) * (it + 2) / 2 <= p) ++it;
    while (it * (it + 1) / 2 > p) --it;
    int jt = p - it * (it + 1) / 2;   // 0..it
    int i0 = it * T64, j0 = jt * T64;
    int tid = threadIdx.x;
    const double* xb  = xtp + (size_t)b * Nq * C2q;
    const double* x2b = x2p + (size_t)b * Nq;
    int wv = tid >> 6, ln = tid & 63;
    int l15 = ln & 15, l4 = ln >> 4;
    int mode = mfma_mode_probe(l4, l15);

    if (mode < 2) {
        int rw[4];
        #pragma unroll
        for (int v = 0; v < 4; v++) rw[v] = (mode == 0) ? (4 * l4 + v) : (l4 + 4 * v);
        int rbase = i0 + wv * 16;
        double a_reg[4][8];
        const double* arow = xb + (size_t)(rbase + l15) * C2q + l4;
        #pragma unroll
        for (int kc = 0; kc < 4; kc++)
            #pragma unroll
            for (int st = 0; st < 8; st++)
                a_reg[kc][st] = arow[kc * KC + 4 * st];
        double x2i[4];
        #pragma unroll
        for (int v = 0; v < 4; v++) x2i[v] = x2b[rbase + rw[v]];
        // prologue: stage kc=0 -> buf0
        #pragma unroll
        for (int w = 0; w < 4; w++) {
            int idx = tid + w * 256; int r = idx >> 4, c = (idx & 15) * 2;
            *(double2*)&sBB[0][r][c] = *(const double2*)&xb[(size_t)(j0 + r) * C2q + c];
        }
        if (tid < T64) sx2j[tid] = x2b[j0 + tid];
        __syncthreads();
        d64x4 acc[4];
        #pragma unroll
        for (int bc = 0; bc < 4; bc++)
            #pragma unroll
            for (int v = 0; v < 4; v++) acc[bc][v] = 0.0;
        #pragma unroll
        for (int kc = 0; kc < 4; kc++) {
            const int cb = kc & 1, nb = cb ^ 1;
            const bool hn = (kc < 3);
            double2 sreg[4];
            if (hn) {
                #pragma unroll
                for (int w = 0; w < 4; w++) {
                    int idx = tid + w * 256; int r = idx >> 4, c = (idx & 15) * 2;
                    sreg[w] = *(const double2*)&xb[(size_t)(j0 + r) * C2q + (kc + 1) * KC + c];
                }
            }
            #pragma unroll
            for (int st = 0; st < 8; st++) {
                double av = a_reg[kc][st];
                #pragma unroll
                for (int bc = 0; bc < 4; bc++) {
                    double bv = sBB[cb][bc * 16 + l15][4 * st + l4];
                    acc[bc] = __builtin_amdgcn_mfma_f64_16x16x4f64(av, bv, acc[bc], 0, 0, 0);
                }
            }
            if (hn) {
                #pragma unroll
                for (int w = 0; w < 4; w++) {
                    int idx = tid + w * 256; int r = idx >> 4, c = (idx & 15) * 2;
                    *(double2*)&sBB[nb][r][c] = sreg[w];
                }
            }
            __syncthreads();
        }
        double mn[4];
        #pragma unroll
        for (int v = 0; v < 4; v++) mn[v] = DBL_MAX;
        #pragma unroll
        for (int bc = 0; bc < 4; bc++) {
            int cg = j0 + bc * 16 + l15;        // global col rank
            double xj = sx2j[bc * 16 + l15];
            #pragma unroll
            for (int v = 0; v < 4; v++) {
                double d2 = x2i[v] + xj - 2.0 * acc[bc][v];
                bool valid = (jt < it) || (cg < rbase + rw[v]);   // strict predecessor
                if (valid) mn[v] = fmin(mn[v], d2);
            }
        }
        for (int m = 1; m <= 8; m <<= 1) {
            #pragma unroll
            for (int v = 0; v < 4; v++) mn[v] = fmin(mn[v], __shfl_xor(mn[v], m));
        }
        if (l15 == 0) {
            #pragma unroll
            for (int v = 0; v < 4; v++)
                pminP[(size_t)jt * BNq + b * Nq + rbase + rw[v]] = mn[v];
        }
    } else {
        // scalar insurance path (never taken on validated HW): k-ascending dot,
        // bitwise consistent with pass1's VALU fallback accumulation order.
        int rl = tid & 63;
        int cg4 = tid >> 6;
        int r = i0 + rl;
        double x2i = x2b[r];
        const double* xr = xb + (size_t)r * C2q;
        double mn = DBL_MAX;
        for (int cc = 0; cc < 16; cc++) {
            int cglob = j0 + cg4 * 16 + cc;
            if (jt == it && cglob >= r) continue;
            const double* xc = xb + (size_t)cglob * C2q;
            double dot = 0.0;
            for (int k = 0; k < C2q; k++) dot += xr[k] * xc[k];
            double d2 = x2i + x2b[cglob] - 2.0 * dot;
            mn = fmin(mn, d2);
        }
        sp[cg4][rl] = mn;
        __syncthreads();
        if (cg4 == 0) {
            mn = fmin(fmin(sp[0][rl], sp[1][rl]), fmin(sp[2][rl], sp[3][rl]));
            pminP[(size_t)jt * BNq + b * Nq + r] = mn;
        }
    }
}

// merge triangular partials -> score (scatter through perm)
__global__ void ctm_merge2t(const double* __restrict__ pminP, const double* __restrict__ maxd2,
                            const double* __restrict__ density, const int* __restrict__ perm,
                            double* score) {
    int t = blockIdx.x * blockDim.x + threadIdx.x;
    if (t >= BNq) return;
    int b = t / Nq;
    int rr = t - b * Nq;
    int it = rr >> 6;
    double m = DBL_MAX;
    for (int jt = 0; jt <= it; jt++) m = fmin(m, pminP[(size_t)jt * BNq + t]);
    double mm = fmin(maxd2[b], m);
    int orig = b * Nq + perm[t];
    score[orig] = sqrt(fmax(mm, 0.0)) / sqrt((double)C2q) * density[orig];
}

// pass2 (recompute fallback tier, v4.0): min d2 over higher-density j
__global__ __launch_bounds__(256, 2)
void ctm_pass2(const double* __restrict__ xt, const double* __restrict__ x2,
               const double* __restrict__ density, double* pmin) {
    __shared__ double sBB[2][T64][LDP];
    __shared__ double sx2j[2][T64];
    __shared__ double sdj[2][T64];
    int blk = blockIdx.x;
    int b  = blk & (Bq - 1);
    int s  = (blk >> 2) & (NSPL - 1);
    int it = blk >> 5;
    int tid = threadIdx.x;
    const double* xtb = xt + (size_t)b * Nq * C2q;
    const double* x2b = x2 + (size_t)b * Nq;
    const double* db  = density + (size_t)b * Nq;
    int i0 = it * T64;
    int jt_beg = c_spl[s], jt_end = c_spl[s + 1];

    int wv = tid >> 6, ln = tid & 63;
    int l15 = ln & 15, l4 = ln >> 4;
    int mode = mfma_mode_probe(l4, l15);

    if (mode < 2) {
        int rw[4];
        #pragma unroll
        for (int v = 0; v < 4; v++) rw[v] = (mode == 0) ? (4 * l4 + v) : (l4 + 4 * v);
        int rbase = i0 + wv * 16;
        double a_reg[4][8];
        const double* arow = xtb + (size_t)(i0 + wv * 16 + l15) * C2q + l4;
        #pragma unroll
        for (int kc = 0; kc < 4; kc++)
            #pragma unroll
            for (int st = 0; st < 8; st++)
                a_reg[kc][st] = arow[kc * KC + 4 * st];
        double x2i[4], di[4], mn[4];
        #pragma unroll
        for (int v = 0; v < 4; v++) {
            x2i[v] = x2b[rbase + rw[v]];
            di[v]  = db[rbase + rw[v]];
            mn[v]  = DBL_MAX;
        }
        {
            int j0 = jt_beg * T64;
            #pragma unroll
            for (int w = 0; w < 4; w++) {
                int idx = tid + w * 256; int r = idx >> 4, c = (idx & 15) * 2;
                *(double2*)&sBB[0][r][c] = *(const double2*)&xtb[(size_t)(j0 + r) * C2q + c];
            }
            if (tid < T64) { sx2j[0][tid] = x2b[j0 + tid]; sdj[0][tid] = db[j0 + tid]; }
        }
        __syncthreads();
        int q = 0;
        for (int jt = jt_beg; jt < jt_end; jt++) {
            int j0 = jt * T64;
            d64x4 acc[4];
            #pragma unroll
            for (int bc = 0; bc < 4; bc++)
                #pragma unroll
                for (int v = 0; v < 4; v++) acc[bc][v] = 0.0;
            #pragma unroll
            for (int kc = 0; kc < 4; kc++) {
                const int cb = kc & 1, nb = cb ^ 1, nkc = (kc + 1) & 3;
                const bool lastk = (kc == 3);
                bool hn = !lastk || (jt + 1 < jt_end);
                int nj0 = lastk ? j0 + T64 : j0;
                double2 sreg[4]; double xr = 0.0, dr = 0.0;
                if (hn) {
                    #pragma unroll
                    for (int w = 0; w < 4; w++) {
                        int idx = tid + w * 256; int r = idx >> 4, c = (idx & 15) * 2;
                        sreg[w] = *(const double2*)&xtb[(size_t)(nj0 + r) * C2q + nkc * KC + c];
                    }
                    if (lastk && tid < T64) { xr = x2b[nj0 + tid]; dr = db[nj0 + tid]; }
                }
                #pragma unroll
                for (int st = 0; st < 8; st++) {
                    double av = a_reg[kc][st];
                    #pragma unroll
                    for (int bc = 0; bc < 4; bc++) {
                        double bv = sBB[cb][bc * 16 + l15][4 * st + l4];
                        acc[bc] = __builtin_amdgcn_mfma_f64_16x16x4f64(av, bv, acc[bc], 0, 0, 0);
                    }
                }
                if (hn) {
                    #pragma unroll
                    for (int w = 0; w < 4; w++) {
                        int idx = tid + w * 256; int r = idx >> 4, c = (idx & 15) * 2;
                        *(double2*)&sBB[nb][r][c] = sreg[w];
                    }
                    if (lastk && tid < T64) { sx2j[q ^ 1][tid] = xr; sdj[q ^ 1][tid] = dr; }
                }
                __syncthreads();
            }
            #pragma unroll
            for (int bc = 0; bc < 4; bc++) {
                double xj = sx2j[q][bc * 16 + l15];
                double dj = sdj[q][bc * 16 + l15];
                #pragma unroll
                for (int v = 0; v < 4; v++) {
                    double d2 = x2i[v] + xj - 2.0 * acc[bc][v];
                    if (dj > di[v]) mn[v] = fmin(mn[v], d2);
                }
            }
            q ^= 1;
        }
        for (int m = 1; m <= 8; m <<= 1) {
            #pragma unroll
            for (int v = 0; v < 4; v++) mn[v] = fmin(mn[v], __shfl_xor(mn[v], m));
        }
        if (l15 == 0) {
            #pragma unroll
            for (int v = 0; v < 4; v++) {
                int gi = b * Nq + rbase + rw[v];
                pmin[(size_t)s * BNq + gi] = mn[v];
            }
        }
    } else {
        double (*sA)[LDP] = sBB[0];
        double (*sB)[LDP] = sBB[1];
        int tx = tid & 15, ty = tid >> 4;
        double x2i[4], di[4], mn[4];
        #pragma unroll
        for (int r = 0; r < 4; r++) {
            x2i[r] = x2b[i0 + ty + 16 * r];
            di[r]  = db[i0 + ty + 16 * r];
            mn[r]  = DBL_MAX;
        }
        for (int jt = jt_beg; jt < jt_end; jt++) {
            int j0 = jt * T64;
            double acc[4][4];
            #pragma unroll
            for (int r = 0; r < 4; r++)
                #pragma unroll
                for (int q = 0; q < 4; q++) acc[r][q] = 0.0;
            for (int kc = 0; kc < 4; kc++) {
                __syncthreads();
                #pragma unroll
                for (int idx = tid; idx < T64 * KC / 2; idx += 256) {
                    int r = idx >> 4, c = (idx & 15) * 2;
                    *(double2*)&sA[r][c] = *(const double2*)&xtb[(size_t)(i0 + r) * C2q + kc * KC + c];
                    *(double2*)&sB[r][c] = *(const double2*)&xtb[(size_t)(j0 + r) * C2q + kc * KC + c];
                }
                if (kc == 0 && tid < T64) { sx2j[0][tid] = x2b[j0 + tid]; sdj[0][tid] = db[j0 + tid]; }
                __syncthreads();
                #pragma unroll 4
                for (int cc = 0; cc < KC; cc += 2) {
                    double2 xi[4], xj[4];
                    #pragma unroll
                    for (int r = 0; r < 4; r++) xi[r] = *(const double2*)&sA[ty + 16 * r][cc];
                    #pragma unroll
                    for (int q = 0; q < 4; q++) xj[q] = *(const double2*)&sB[tx + 16 * q][cc];
                    #pragma unroll
                    for (int r = 0; r < 4; r++)
                        #pragma unroll
                        for (int q = 0; q < 4; q++) acc[r][q] += xi[r].x * xj[q].x;
                    #pragma unroll
                    for (int r = 0; r < 4; r++)
                        #pragma unroll
                        for (int q = 0; q < 4; q++) acc[r][q] += xi[r].y * xj[q].y;
                }
            }
            #pragma unroll
            for (int r = 0; r < 4; r++)
                #pragma unroll
                for (int q = 0; q < 4; q++) {
                    double d2 = x2i[r] + sx2j[0][tx + 16 * q] - 2.0 * acc[r][q];
                    if (sdj[0][tx + 16 * q] > di[r]) mn[r] = fmin(mn[r], d2);
                }
        }
        for (int m = 1; m <= 8; m <<= 1) {
            #pragma unroll
            for (int r = 0; r < 4; r++) mn[r] = fmin(mn[r], __shfl_xor(mn[r], m));
        }
        if (tx == 0) {
            #pragma unroll
            for (int r = 0; r < 4; r++) {
                int gi = b * Nq + i0 + ty + 16 * r;
                pmin[(size_t)s * BNq + gi] = mn[r];
            }
        }
    }
}

// merge pass2 partials -> score (recompute path)
__global__ void ctm_merge2(const double* __restrict__ pmin, const double* __restrict__ maxd2,
                           const double* __restrict__ density, double* score) {
    int t = blockIdx.x * blockDim.x + threadIdx.x;
    if (t >= BNq) return;
    int b = t / Nq;
    double m = pmin[t];
    #pragma unroll
    for (int s = 1; s < NSPL; s++) m = fmin(m, pmin[(size_t)s * BNq + t]);
    double mm = fmin(maxd2[b], m);
    score[t] = sqrt(fmax(mm, 0.0)) / sqrt((double)C2q) * density[t];
}

// top-784 with jax.lax.top_k semantics: total order (score desc, idx asc).
__global__ __launch_bounds__(1024)
void ctm_sort(const double* __restrict__ score, int* index_down) {
    __shared__ double s[4096];
    __shared__ int   si[4096];
    int b = blockIdx.x, tid = threadIdx.x;
    for (int i = tid; i < 4096; i += 1024) {
        if (i < Nq) {
            double v = score[b * Nq + i];
            s[i] = isnan(v) ? -DBL_MAX : v;
            si[i] = i;
        } else { s[i] = -DBL_MAX; si[i] = 0x7fffffff; }
    }
    __syncthreads();
    for (int k = 2; k <= 4096; k <<= 1) {
        for (int j = k >> 1; j > 0; j >>= 1) {
            for (int i = tid; i < 4096; i += 1024) {
                int ixj = i ^ j;
                if (ixj > i) {
                    double s1 = s[i], s2 = s[ixj];
                    int i1 = si[i], i2 = si[ixj];
                    bool before_ij = (s1 > s2) || (s1 == s2 && i1 < i2);
                    bool before_ji = (s2 > s1) || (s2 == s1 && i2 < i1);
                    bool doswap = ((i & k) == 0) ? before_ji : before_ij;
                    if (doswap) { s[i] = s2; s[ixj] = s1; si[i] = i2; si[ixj] = i1; }
                }
            }
            __syncthreads();
        }
    }
    for (int t = tid; t < NSq; t += 1024) {
        int v = si[t];
        index_down[b * NSq + t] = ((unsigned)v < (unsigned)Nq) ? v : 0;
    }
}

// assign: argmin over centers (lexicographic (d,sc) min), split x2.
__global__ __launch_bounds__(256, 2)
void ctm_assign(const double* __restrict__ xt, const double* __restrict__ x2,
                const int* __restrict__ index_down, double* pbd, int* pbs) {
    __shared__ double sBB[2][T64][LDP];
    __shared__ double sx2c[T64];
    __shared__ int    sidx[T64];
    int blk = blockIdx.x;
    int b  = blk & (Bq - 1);
    int s  = (blk >> 2) & (NSPA - 1);
    int it = blk >> 3;
    int tid = threadIdx.x;
    const double* xtb = xt + (size_t)b * Nq * C2q;
    const double* x2b = x2 + (size_t)b * Nq;
    int i0 = it * T64;
    int jt_beg = c_spla[s], jt_end = c_spla[s + 1];

    int wv = tid >> 6, ln = tid & 63;
    int l15 = ln & 15, l4 = ln >> 4;
    int mode = mfma_mode_probe(l4, l15);

    if (mode < 2) {
        int rw[4];
        #pragma unroll
        for (int v = 0; v < 4; v++) rw[v] = (mode == 0) ? (4 * l4 + v) : (l4 + 4 * v);
        int rbase = i0 + wv * 16;
        double a_reg[4][8];
        const double* arow = xtb + (size_t)(i0 + wv * 16 + l15) * C2q + l4;
        #pragma unroll
        for (int kc = 0; kc < 4; kc++)
            #pragma unroll
            for (int st = 0; st < 8; st++)
                a_reg[kc][st] = arow[kc * KC + 4 * st];
        double x2i[4], bd[4];
        int bs[4];
        #pragma unroll
        for (int v = 0; v < 4; v++) { x2i[v] = x2b[rbase + rw[v]]; bd[v] = DBL_MAX; bs[v] = NSq - 1; }
        for (int jt = jt_beg; jt < jt_end; jt++) {
            int j0 = jt * T64;
            __syncthreads();
            if (tid < T64) {
                int j = index_down[b * NSq + min(j0 + tid, NSq - 1)];
                sidx[tid] = j;
                sx2c[tid] = x2b[j];
            }
            __syncthreads();
            d64x4 acc[4];
            #pragma unroll
            for (int bc = 0; bc < 4; bc++)
                #pragma unroll
                for (int v = 0; v < 4; v++) acc[bc][v] = 0.0;
            for (int kc = 0; kc < 4; kc++) {
                if (kc) __syncthreads();
                #pragma unroll
                for (int idx = tid; idx < T64 * KC / 2; idx += 256) {
                    int r = idx >> 4, c = (idx & 15) * 2;
                    *(double2*)&sBB[0][r][c] = *(const double2*)&xtb[(size_t)sidx[r] * C2q + kc * KC + c];
                }
                __syncthreads();
                #pragma unroll
                for (int st = 0; st < 8; st++) {
                    double av = a_reg[kc][st];
                    #pragma unroll
                    for (int bc = 0; bc < 4; bc++) {
                        double bv = sBB[0][bc * 16 + l15][4 * st + l4];
                        acc[bc] = __builtin_amdgcn_mfma_f64_16x16x4f64(av, bv, acc[bc], 0, 0, 0);
                    }
                }
            }
            #pragma unroll
            for (int bc = 0; bc < 4; bc++) {
                int sc = j0 + bc * 16 + l15;
                double xc = sx2c[bc * 16 + l15];
                #pragma unroll
                for (int v = 0; v < 4; v++) {
                    double d = fmax(x2i[v] + xc - 2.0 * acc[bc][v], 0.0);
                    if (sc < NSq && (d < bd[v] || (d == bd[v] && sc < bs[v]))) { bd[v] = d; bs[v] = sc; }
                }
            }
        }
        for (int m = 1; m <= 8; m <<= 1) {
            #pragma unroll
            for (int v = 0; v < 4; v++) {
                double pd = __shfl_xor(bd[v], m);
                int    ps = __shfl_xor(bs[v], m);
                if (pd < bd[v] || (pd == bd[v] && ps < bs[v])) { bd[v] = pd; bs[v] = ps; }
            }
        }
        if (l15 == 0) {
            #pragma unroll
            for (int v = 0; v < 4; v++) {
                int gi = b * Nq + rbase + rw[v];
                pbd[(size_t)s * BNq + gi] = bd[v];
                pbs[(size_t)s * BNq + gi] = bs[v];
            }
        }
    } else {
        double (*sA)[LDP] = sBB[0];
        double (*sB)[LDP] = sBB[1];
        int tx = tid & 15, ty = tid >> 4;
        double x2i[4], bd[4];
        int bs[4];
        #pragma unroll
        for (int r = 0; r < 4; r++) { x2i[r] = x2b[i0 + ty + 16 * r]; bd[r] = DBL_MAX; bs[r] = NSq - 1; }
        for (int jt = jt_beg; jt < jt_end; jt++) {
            int j0 = jt * T64;
            __syncthreads();
            if (tid < T64) {
                int j = index_down[b * NSq + min(j0 + tid, NSq - 1)];
                sidx[tid] = j;
                sx2c[tid] = x2b[j];
            }
            __syncthreads();
            double acc[4][4];
            #pragma unroll
            for (int r = 0; r < 4; r++)
                #pragma unroll
                for (int q = 0; q < 4; q++) acc[r][q] = 0.0;
            for (int kc = 0; kc < 4; kc++) {
                if (kc) __syncthreads();
                #pragma unroll
                for (int idx = tid; idx < T64 * KC / 2; idx += 256) {
                    int r = idx >> 4, c = (idx & 15) * 2;
                    *(double2*)&sA[r][c] = *(const double2*)&xtb[(size_t)(i0 + r) * C2q + kc * KC + c];
                    *(double2*)&sB[r][c] = *(const double2*)&xtb[(size_t)sidx[r] * C2q + kc * KC + c];
                }
                __syncthreads();
                #pragma unroll 4
                for (int cc = 0; cc < KC; cc += 2) {
                    double2 xi[4], xj[4];
                    #pragma unroll
                    for (int r = 0; r < 4; r++) xi[r] = *(const double2*)&sA[ty + 16 * r][cc];
                    #pragma unroll
                    for (int q = 0; q < 4; q++) xj[q] = *(const double2*)&sB[tx + 16 * q][cc];
                    #pragma unroll
                    for (int r = 0; r < 4; r++)
                        #pragma unroll
                        for (int q = 0; q < 4; q++) acc[r][q] += xi[r].x * xj[q].x;
                    #pragma unroll
                    for (int r = 0; r < 4; r++)
                        #pragma unroll
                        for (int q = 0; q < 4; q++) acc[r][q] += xi[r].y * xj[q].y;
                }
            }
            #pragma unroll
            for (int r = 0; r < 4; r++)
                #pragma unroll
                for (int q = 0; q < 4; q++) {
                    int sc = j0 + tx + 16 * q;
                    double d = fmax(x2i[r] + sx2c[tx + 16 * q] - 2.0 * acc[r][q], 0.0);
                    if (sc < NSq && (d < bd[r] || (d == bd[r] && sc < bs[r]))) { bd[r] = d; bs[r] = sc; }
                }
        }
        for (int m = 1; m <= 8; m <<= 1) {
            #pragma unroll
            for (int r = 0; r < 4; r++) {
                double pd = __shfl_xor(bd[r], m);
                int    ps = __shfl_xor(bs[r], m);
                if (pd < bd[r] || (pd == bd[r] && ps < bs[r])) { bd[r] = pd; bs[r] = ps; }
            }
        }
        if (tx == 0) {
            #pragma unroll
            for (int r = 0; r < 4; r++) {
                int gi = b * Nq + i0 + ty + 16 * r;
                pbd[(size_t)s * BNq + gi] = bd[r];
                pbs[(size_t)s * BNq + gi] = bs[r];
            }
        }
    }
}

// merge assign partials (lexicographic (d,sc) min == first-min semantics)
__global__ void ctm_merge3(const double* __restrict__ pbd, const int* __restrict__ pbs,
                           int* idx_cluster) {
    int t = blockIdx.x * blockDim.x + threadIdx.x;
    if (t >= BNq) return;
    double d0 = pbd[t];          int s0 = pbs[t];
    double d1 = pbd[BNq + t];    int s1 = pbs[BNq + t];
    bool take1 = (d1 < d0) || (d1 == d0 && s1 < s0);
    idx_cluster[t] = take1 ? s1 : s0;
}

__global__ void ctm_override(const int* __restrict__ index_down, int* idx_cluster) {
    int t = blockIdx.x * blockDim.x + threadIdx.x;
    if (t >= Bq * NSq) return;
    int b = t / NSq, sc = t - b * NSq;
    int j = index_down[t];
    if ((unsigned)j < (unsigned)Nq) idx_cluster[b * Nq + j] = sc;
}

__global__ void ctm_zeromerged(double* xmerged) {
    int t = blockIdx.x * blockDim.x + threadIdx.x;
    if (t < Bq * NSq * C2q) xmerged[t] = 0.0;
}

__global__ void ctm_merge_w(const int* __restrict__ idx_cluster, const double* __restrict__ weightv,
                            double* allwc) {
    int t = blockIdx.x * blockDim.x + threadIdx.x;
    if (t >= BNq) return;
    int b = t / Nq;
    int sc = min(max(idx_cluster[t], 0), NSq - 1);
    atomicAdd(&allwc[b * NSq + sc], weightv[t]);
}

// merge_x, (point,channel)-parallel: one coalesced atomic per thread.
__global__ void ctm_merge_x(const int* __restrict__ idx_cluster, const double* __restrict__ weightv,
                            const double* __restrict__ allwc, const double* __restrict__ xt,
                            double* nw, double* xmerged) {
    int id = blockIdx.x * blockDim.x + threadIdx.x;
    if (id >= BNq * C2q) return;
    int t = id / C2q, c = id - t * C2q;
    int b = t / Nq;
    int sc = min(max(idx_cluster[t], 0), NSq - 1);
    double nv = weightv[t] / (allwc[b * NSq + sc] + 1e-6);
    if (c == 0) nw[t] = nv;
    atomicAdd(&xmerged[((size_t)(b * NSq + sc)) * C2q + c], xt[(size_t)t * C2q + c] * nv);
}

__global__ void ctm_out0(const double* __restrict__ xmerged, float* out) {
    int t = blockIdx.x * blockDim.x + threadIdx.x;
    if (t >= Bq * NSq * C2q) return;
    out[t] = (float)xmerged[t];
}

__global__ void ctm_out12(const int* __restrict__ idx_agg, const int* __restrict__ idx_cluster,
                          const double* __restrict__ nw, const float* __restrict__ aggw,
                          float* out1, double* awd, double* maxawd) {
    int t = blockIdx.x * blockDim.x + threadIdx.x;
    if (t >= BNq) return;
    int b = t / Nq;
    int tok = clampTok(idx_agg[t]);
    int sc = idx_cluster[b * Nq + tok];
    out1[t] = (float)sc;
    double a = (double)aggw[t] * nw[b * Nq + tok];
    awd[t] = a;
    atomicMaxPosD(&maxawd[b], a);
}

__global__ void ctm_out2(const double* __restrict__ awd, const double* __restrict__ maxawd, float* out2) {
    int t = blockIdx.x * blockDim.x + threadIdx.x;
    if (t >= BNq) return;
    int b = t / Nq;
    out2[t] = (float)(awd[t] / maxawd[b]);
}

// ---------------------------------------------------------------------------
extern "C" void kernel_launch(void* const* d_in, const int* in_sizes, int n_in,
                              void* d_out, int out_size, void* d_ws, size_t ws_size,
                              hipStream_t stream) {
    const float* x     = (const float*)d_in[0];
    const float* loc   = (const float*)d_in[1];
    const int*   idxag = (const int*)  d_in[2];
    const float* aggw  = (const float*)d_in[3];
    const float* convw = (const float*)d_in[4];
    const float* convb = (const float*)d_in[5];
    const float* skipw = (const float*)d_in[6];
    const float* lng   = (const float*)d_in[7];
    const float* lnb   = (const float*)d_in[8];
    const float* confw = (const float*)d_in[9];
    const float* confb = (const float*)d_in[10];
    (void)in_sizes; (void)n_in;

    char* w = (char*)d_ws;
    size_t off = 0;
    auto alloc = [&](size_t bytes) -> void* {
        void* p = w + off; off = (off + bytes + 255) & ~(size_t)255; return p;
    };

    // ---- zero-initialized region (one memset) ----
    int*    cnt56   = (int*)   alloc((size_t)BNq * 4);
    double* allwtok = (double*)alloc((size_t)BNq * 8);
    double* xt      = (double*)alloc((size_t)BNq * C2q * 8);
    double* arena   = (double*)alloc((size_t)Bq * HWq * Cq * 8);   // xmap56T, later xmerged
    double* allwc   = (double*)alloc((size_t)Bq * NSq * 8);
    double* maxawd  = (double*)alloc((size_t)Bq * 8);
    double* maxd2   = (double*)alloc((size_t)Bq * 8);              // atomic max (init 0)
    size_t zero_bytes = off;
    // ---- non-zero region ----
    int*    cell56   = (int*)   alloc((size_t)BNq * 4);
    int*    cell28   = (int*)   alloc((size_t)BNq * 4);
    double* xmap28T  = (double*)alloc((size_t)Bq * HWOq * C2q * 8);
    float*  wT       = (float*) alloc((size_t)C2q * Cq * 9 * 4);
    double* x2       = (double*)alloc((size_t)BNq * 8);
    double* density  = (double*)alloc((size_t)BNq * 8);
    double* score    = (double*)alloc((size_t)BNq * 8);
    int*    indexdn  = (int*)   alloc((size_t)Bq * NSq * 4);
    int*    idxclu   = (int*)   alloc((size_t)BNq * 4);
    double* nw       = (double*)alloc((size_t)BNq * 8);
    double* weightv  = (double*)alloc((size_t)BNq * 8);
    double* awd      = (double*)alloc((size_t)BNq * 8);
    double* pbest    = (double*)alloc((size_t)NSPL * BNq * KNN * 8);
    double* pmax     = (double*)alloc((size_t)NSPL * BNq * 8);
    double* pmin     = (double*)alloc((size_t)NSPL * BNq * 8);
    double* pbd      = (double*)alloc((size_t)NSPA * BNq * 8);
    int*    pbs      = (int*)   alloc((size_t)NSPA * BNq * 4);
    size_t required = off;
    // ---- triangular-pass2 tier (~+18 MB) ----
    int*    perm     = (int*)   alloc((size_t)BNq * 4);
    double* x2p      = (double*)alloc((size_t)BNq * 8);
    double* xtp      = (double*)alloc((size_t)BNq * C2q * 8);
    double* pminP    = (double*)alloc((size_t)NIT64 * BNq * 8);
    size_t required_tri = off;

    const int tb = 256;
    float* out = (float*)d_out;

    if (ws_size < required) {
        ctm_fallback<<<(out_size + tb - 1) / tb, tb, 0, stream>>>(out, out_size);
        return;
    }
    const bool tri = (ws_size >= required_tri);

    double* xmap56T = arena;
    double* xmerged = arena;   // reused after conv; re-zeroed below

    hipMemsetAsync(d_ws, 0, zero_bytes, stream);

    ctm_prep<<<(BNq + tb - 1) / tb, tb, 0, stream>>>(loc, idxag, aggw, cell56, cell28, cnt56, allwtok);
    ctm_wt<<<((C2q * Cq * 9) + tb - 1) / tb, tb, 0, stream>>>(convw, wT);
    ctm_t2m<<<((BNq * Cq) + tb - 1) / tb, tb, 0, stream>>>(x, idxag, cell56, cnt56, xmap56T);
    ctm_conv<<<Bq * (HWOq / 2), 256, 0, stream>>>(xmap56T, wT, convb, xmap28T);
    ctm_m2t<<<((BNq * C2q) + tb - 1) / tb, tb, 0, stream>>>(xmap28T, aggw, idxag, cell28, allwtok, xt);
    ctm_finalize<<<BNq, C2q, 0, stream>>>(xt, x, skipw, lng, lnb, confw, confb, x2, weightv);
    ctm_pass1<<<Bq * NSPL * NIT64, 256, 0, stream>>>(xt, x2, pbest, pmax);
    ctm_merge1<<<(BNq + tb - 1) / tb, tb, 0, stream>>>(pbest, pmax, density, maxd2);
    if (tri) {
        ctm_sortd<<<Bq, 1024, 0, stream>>>(density, perm);
        ctm_perm<<<((BNq * C2q) + tb - 1) / tb, tb, 0, stream>>>(xt, x2, perm, xtp, x2p);
        ctm_pass2t<<<Bq * NPAIR, 256, 0, stream>>>(xtp, x2p, pminP);
        ctm_merge2t<<<(BNq + tb - 1) / tb, tb, 0, stream>>>(pminP, maxd2, density, perm, score);
    } else {
        ctm_pass2<<<Bq * NSPL * NIT64, 256, 0, stream>>>(xt, x2, density, pmin);
        ctm_merge2<<<(BNq + tb - 1) / tb, tb, 0, stream>>>(pmin, maxd2, density, score);
    }
    ctm_sort<<<Bq, 1024, 0, stream>>>(score, indexdn);
    ctm_assign<<<Bq * NSPA * NIT64, 256, 0, stream>>>(xt, x2, indexdn, pbd, pbs);
    ctm_merge3<<<(BNq + tb - 1) / tb, tb, 0, stream>>>(pbd, pbs, idxclu);
    ctm_override<<<((Bq * NSq) + tb - 1) / tb, tb, 0, stream>>>(indexdn, idxclu);
    ctm_zeromerged<<<((Bq * NSq * C2q) + tb - 1) / tb, tb, 0, stream>>>(xmerged);
    ctm_merge_w<<<(BNq + tb - 1) / tb, tb, 0, stream>>>(idxclu, weightv, allwc);
    ctm_merge_x<<<((BNq * C2q) + tb - 1) / tb, tb, 0, stream>>>(idxclu, weightv, allwc, xt, nw, xmerged);

    ctm_out0<<<((Bq * NSq * C2q) + tb - 1) / tb, tb, 0, stream>>>(xmerged, out);
    ctm_out12<<<(BNq + tb - 1) / tb, tb, 0, stream>>>(idxag, idxclu, nw, aggw,
                                                      out + (size_t)Bq * NSq * C2q, awd, maxawd);
    ctm_out2<<<(BNq + tb - 1) / tb, tb, 0, stream>>>(awd, maxawd,
                                                     out + (size_t)Bq * NSq * C2q + BNq);
}

// Round 6
// 1217.919 us; speedup vs baseline: 1.0252x; 1.0252x over previous
//
#include <hip/hip_runtime.h>
#include <math.h>
#include <float.h>

// Problem constants: B=4, N=3136, C=64, C2=128, H=W=56, stride2 -> 28x28,
// Ns = ceil(N*0.25) = 784, k = 5.  Inputs are float32/int32 per reference.
#define Bq   4
#define Nq   3136
#define Cq   64
#define C2q  128
#define Hq   56
#define Wq   56
#define HWq  (Hq*Wq)
#define HOq  28
#define WOq  28
#define HWOq (HOq*WOq)
#define NSq  784
#define KNN  5
#define BNq  (Bq*Nq)

#define T64   64             // i/j tile for distance kernels
#define KC    32             // K chunk
#define NIT64 (Nq/T64)       // 49 i-tiles (exact)
#define NPAIR (NIT64*(NIT64+1)/2)  // 1225 lower-tri tile pairs
#define NSPL  8              // j-range splits (grid 1568)
#define NSPA  2              // assign center-range splits
#define LDP   34             // LDS row stride (even -> 16B-aligned double2)

__device__ __constant__ int c_spl[NSPL + 1]  = {0, 7, 13, 19, 25, 31, 37, 43, 49};
__device__ __constant__ int c_spla[NSPA + 1] = {0, 7, 13};

typedef unsigned int   u32;
typedef unsigned long long u64;
typedef __attribute__((ext_vector_type(4))) double d64x4;

static __device__ __forceinline__ void atomicMaxPosD(double* p, double v) {
    atomicMax((u64*)p, (u64)__double_as_longlong(v));
}
static __device__ __forceinline__ int clampTok(int t) {
    return min(max(t, 0), Nq - 1);
}

// order-isomorphic f64 <-> u64 map (valid for ALL finite doubles):
// unsigned compare on encD(d) == double compare on d.
static __device__ __forceinline__ u64 encD(double d) {
    u64 u = (u64)__double_as_longlong(d);
    return (u >> 63) ? ~u : (u | 0x8000000000000000ULL);
}
static __device__ __forceinline__ double decD(u64 u) {
    u64 o = (u >> 63) ? (u ^ 0x8000000000000000ULL) : ~u;
    return __longlong_as_double((long long)o);
}
#define ENC_DBL_MAX 0xFFEFFFFFFFFFFFFFULL   // encD(DBL_MAX)

// sorted-ascending insert into 5-list (static indices after unroll)
static __device__ __forceinline__ void ins5(double* a, double v) {
    if (v < a[KNN - 1]) {
        a[KNN - 1] = v;
        #pragma unroll
        for (int m = KNN - 1; m > 0; m--)
            if (a[m] < a[m - 1]) { double t = a[m]; a[m] = a[m - 1]; a[m - 1] = t; }
    }
}
static __device__ __forceinline__ void cex(double& a, double& b) {
    double lo = fmin(a, b), hi = fmax(a, b); a = lo; b = hi;
}
// merge two ascending 5-lists, keep 5 smallest ascending.  STATIC INDICES ONLY.
static __device__ __forceinline__ void merge5(double* a, const double* p) {
    double t0 = fmin(a[0], p[4]);
    double t1 = fmin(a[1], p[3]);
    double t2 = fmin(a[2], p[2]);
    double t3 = fmin(a[3], p[1]);
    double t4 = fmin(a[4], p[0]);
    cex(t0, t1); cex(t1, t2); cex(t2, t3); cex(t3, t4);
    cex(t0, t1); cex(t1, t2); cex(t2, t3);
    cex(t0, t1); cex(t1, t2);
    cex(t0, t1);
    a[0] = t0; a[1] = t1; a[2] = t2; a[3] = t3; a[4] = t4;
}

// ---------------------------------------------------------------------------
// f64 MFMA layout probe (validated on HW in R2-R5: mode 0/1 path taken).
// ---------------------------------------------------------------------------
static __device__ __forceinline__ int mfma_mode_probe(int l4, int l15) {
    d64x4 p;
    #pragma unroll
    for (int v = 0; v < 4; v++) p[v] = 0.0;
    double a1 = (l4 == 0) ? (double)(16 * l15) : 0.0;
    double b1 = (l4 == 0) ? 1.0 : 0.0;
    p = __builtin_amdgcn_mfma_f64_16x16x4f64(a1, b1, p, 0, 0, 0);   // D += 16*m
    double a2 = (l4 == 0) ? 1.0 : 0.0;
    double b2 = (l4 == 0) ? (double)l15 : 0.0;
    p = __builtin_amdgcn_mfma_f64_16x16x4f64(a2, b2, p, 0, 0, 0);   // D += n
    bool ok0 = true, ok1 = true;
    #pragma unroll
    for (int v = 0; v < 4; v++) {
        ok0 = ok0 && (p[v] == (double)(16 * (4 * l4 + v) + l15));
        ok1 = ok1 && (p[v] == (double)(16 * (l4 + 4 * v) + l15));
    }
    return __all(ok0) ? 0 : (__all(ok1) ? 1 : 2);
}

// ---- jax threefry2x32 noise: uniform(key(42), (4,3136)) -------------------
static __device__ __forceinline__ u32 rotl32(u32 x, int d) { return (x << d) | (x >> (32 - d)); }
static __device__ __forceinline__ float tf_uniform(int t) {
    const u32 k0 = 0u, k1 = 42u;
    const u32 ks2 = k0 ^ k1 ^ 0x1BD11BDAu;
    u32 ks[3] = { k0, k1, ks2 };
    bool lo = (t < 6272);
    u32 cx0 = lo ? (u32)t : (u32)(t - 6272);
    u32 cx1 = lo ? (u32)(t + 6272) : (u32)t;
    u32 x0 = cx0 + ks[0];
    u32 x1 = cx1 + ks[1];
    const int R0[4] = {13, 15, 26, 6};
    const int R1[4] = {17, 29, 16, 24};
    #pragma unroll
    for (int i = 0; i < 5; i++) {
        const int* rot = (i % 2 == 0) ? R0 : R1;
        #pragma unroll
        for (int r = 0; r < 4; r++) { x0 += x1; x1 = rotl32(x1, rot[r]); x1 ^= x0; }
        x0 += ks[(i + 1) % 3];
        x1 += ks[(i + 2) % 3] + (u32)(i + 1);
    }
    u32 bits = lo ? x0 : x1;
    u32 fb = (bits >> 9) | 0x3f800000u;
    float f; __builtin_memcpy(&f, &fb, 4);
    return f - 1.0f;
}

// ---- grid index: clip(loc,-1,1)*0.5+0.5 -> round-half-even ----------------
static __device__ __forceinline__ int gridIndex(float lx, float ly, int Wd, int Hd) {
    double x = fmin(fmax((double)lx, -1.0), 1.0) * 0.5 + 0.5;
    double y = fmin(fmax((double)ly, -1.0), 1.0) * 0.5 + 0.5;
    int ix = (int)rint(x * (double)(Wd - 1)); ix = min(max(ix, 0), Wd - 1);
    int iy = (int)rint(y * (double)(Hd - 1)); iy = min(max(iy, 0), Hd - 1);
    return iy * Wd + ix;
}

// ---------------------------------------------------------------------------
__global__ void ctm_fallback(float* out, int n) {
    int t = blockIdx.x * blockDim.x + threadIdx.x;
    if (t < n) out[t] = 0.0f;
}

__global__ void ctm_prep(const float* __restrict__ loc, const int* __restrict__ idx_agg,
                         const float* __restrict__ aggw,
                         int* cell56, int* cell28, int* cnt56, double* allwtok) {
    int t = blockIdx.x * blockDim.x + threadIdx.x;
    if (t >= BNq) return;
    int b = t / Nq;
    float lx = loc[2 * t], ly = loc[2 * t + 1];
    int c56 = gridIndex(lx, ly, Wq, Hq);
    int c28 = gridIndex(lx, ly, WOq, HOq);
    cell56[t] = c56; cell28[t] = c28;
    atomicAdd(&cnt56[b * HWq + c56], 1);
    int tok = clampTok(idx_agg[t]);
    atomicAdd(&allwtok[b * Nq + tok], (double)aggw[t]);
}

// t2m, (point,channel)-parallel: one coalesced f64 atomic per thread.
__global__ void ctm_t2m(const float* __restrict__ x, const int* __restrict__ idx_agg,
                        const int* __restrict__ cell56, const int* __restrict__ cnt56,
                        double* xmap56T) {
    int id = blockIdx.x * blockDim.x + threadIdx.x;
    if (id >= BNq * Cq) return;
    int t = id / Cq, c = id - t * Cq;
    int b = t / Nq;
    int cell = cell56[t];
    double v = 1.0 / ((double)cnt56[b * HWq + cell] + 1e-6);
    double xv = (double)x[(size_t)(b * Nq + clampTok(idx_agg[t])) * Cq + c];
    atomicAdd(&xmap56T[((size_t)b * HWq + cell) * Cq + c], xv * v);
}

// one-time weight transpose: wT[(ci*9+tap)*C2q+co] = w[co*Cq*9 + ci*9 + tap]
__global__ void ctm_wt(const float* __restrict__ w, float* wT) {
    int id = blockIdx.x * blockDim.x + threadIdx.x;
    if (id >= C2q * Cq * 9) return;
    int co = id & (C2q - 1);
    int rem = id >> 7;
    int tap = rem % 9;
    int ci = rem / 9;
    wT[id] = w[(size_t)co * Cq * 9 + ci * 9 + tap];
}

// conv 3x3 stride2: block = 2 cells x 128 co, input taps staged in LDS.
__global__ __launch_bounds__(256)
void ctm_conv(const double* __restrict__ xmap56T, const float* __restrict__ wT,
              const float* __restrict__ bias, double* xmap28T) {
    __shared__ double sIn[2][9][Cq];
    int blk = blockIdx.x;
    int b  = blk & (Bq - 1);
    int cp = blk >> 2;              // cell pair index, 0..391
    int tid = threadIdx.x;
    int co = tid & (C2q - 1);
    int cl = tid >> 7;              // 0 or 1
    const double* xb = xmap56T + (size_t)b * HWq * Cq;
    for (int idx = tid; idx < 2 * 9 * Cq; idx += 256) {
        int cell_l = idx / (9 * Cq);
        int rem = idx - cell_l * (9 * Cq);
        int tap = rem >> 6;
        int ci  = rem & 63;
        int cell = 2 * cp + cell_l;
        int ox = cell % WOq, oy = cell / WOq;
        int ky = tap / 3, kx = tap - ky * 3;
        int iy = 2 * oy + ky - 1, ix = 2 * ox + kx - 1;
        double v = 0.0;
        if (iy >= 0 && iy < Hq && ix >= 0 && ix < Wq)
            v = xb[(size_t)(iy * Wq + ix) * Cq + ci];
        sIn[cell_l][tap][ci] = v;
    }
    __syncthreads();
    double acc = (double)bias[co];
    for (int ci = 0; ci < Cq; ci++) {
        #pragma unroll
        for (int tap = 0; tap < 9; tap++)
            acc += sIn[cl][tap][ci] * (double)wT[(size_t)(ci * 9 + tap) * C2q + co];
    }
    int cell = 2 * cp + cl;
    xmap28T[((size_t)b * HWOq + cell) * C2q + co] = acc;
}

// m2t, (point,channel)-parallel: coalesced.
__global__ void ctm_m2t(const double* __restrict__ xmap28T, const float* __restrict__ aggw,
                        const int* __restrict__ idx_agg, const int* __restrict__ cell28,
                        const double* __restrict__ allwtok, double* xt) {
    int id = blockIdx.x * blockDim.x + threadIdx.x;
    if (id >= BNq * C2q) return;
    int t = id / C2q, c = id - t * C2q;
    int b = t / Nq;
    int tok = clampTok(idx_agg[t]);
    double v = (double)aggw[t] / (allwtok[b * Nq + tok] + 1e-6);
    double f = xmap28T[((size_t)b * HWOq + cell28[t]) * C2q + c];
    atomicAdd(&xt[(size_t)(b * Nq + tok) * C2q + c], f * v);
}

// finalize v2: wave-shuffle reductions (4 barriers, was 28).
__global__ __launch_bounds__(C2q)
void ctm_finalize(double* xt, const float* __restrict__ x, const float* __restrict__ skipw,
                  const float* __restrict__ lng, const float* __restrict__ lnb,
                  const float* __restrict__ confw, const float* __restrict__ confb,
                  double* x2o, double* weightv) {
    int bn = blockIdx.x; int c = threadIdx.x;
    int lane = c & 63, w = c >> 6;
    double* row = xt + (size_t)bn * C2q;
    const float* xr = x + (size_t)bn * Cq;
    double acc = row[c];
    const float* sw = skipw + c * Cq;
    #pragma unroll 16
    for (int k = 0; k < Cq; k++) acc += (double)xr[k] * (double)sw[k];
    __shared__ double slot[4][2];
    double s = acc;
    #pragma unroll
    for (int m = 1; m <= 32; m <<= 1) s += __shfl_xor(s, m);
    if (lane == 0) slot[0][w] = s;
    __syncthreads();
    double mu = (slot[0][0] + slot[0][1]) * (1.0 / C2q);
    double d = acc - mu;
    s = d * d;
    #pragma unroll
    for (int m = 1; m <= 32; m <<= 1) s += __shfl_xor(s, m);
    if (lane == 0) slot[1][w] = s;
    __syncthreads();
    double var = (slot[1][0] + slot[1][1]) * (1.0 / C2q);
    double v = d / sqrt(var + 1e-5) * (double)lng[c] + (double)lnb[c];
    row[c] = v;
    s = v * v;
    #pragma unroll
    for (int m = 1; m <= 32; m <<= 1) s += __shfl_xor(s, m);
    if (lane == 0) slot[2][w] = s;
    double s2 = v * (double)confw[c];
    #pragma unroll
    for (int m = 1; m <= 32; m <<= 1) s2 += __shfl_xor(s2, m);
    if (lane == 0) slot[3][w] = s2;
    __syncthreads();
    if (c == 0) {
        x2o[bn] = slot[2][0] + slot[2][1];
        weightv[bn] = exp(slot[3][0] + slot[3][1] + (double)confb[0]);
    }
}

// ---------------------------------------------------------------------------
// Distance kernels v7.0: pass2 = density-sorted lower-triangular tile sweep
// with ZERO extra workspace: rows gathered through perm (assign-style),
// per-row minima folded via u64-ordered atomicMin, perm+pmin2u alias the
// pbest buffer (dead after merge1).  The mask inside tiles is the exact
// reference predicate density[j] > density[i] (tie-safe); the sort only
// guarantees all masked pairs live in lower/diag tiles (51% of tiles).
// d2 chains are bitwise identical to the old recompute pass2 (same MFMA
// order), and fmin-folding is order-invariant -> identical scores.
// ---------------------------------------------------------------------------

// pass1: per row i -> 5 smallest d2 + row max d2 (partial per j-split)
__global__ __launch_bounds__(256, 2)
void ctm_pass1(const double* __restrict__ xt, const double* __restrict__ x2,
               double* pbest, double* pmax) {
    __shared__ double sBB[2][T64][LDP];
    __shared__ double sx2j[2][T64];
    int blk = blockIdx.x;
    int b  = blk & (Bq - 1);
    int s  = (blk >> 2) & (NSPL - 1);
    int it = blk >> 5;
    int tid = threadIdx.x;
    const double* xtb = xt + (size_t)b * Nq * C2q;
    const double* x2b = x2 + (size_t)b * Nq;
    int i0 = it * T64;
    int jt_beg = c_spl[s], jt_end = c_spl[s + 1];

    int wv = tid >> 6, ln = tid & 63;
    int l15 = ln & 15, l4 = ln >> 4;
    int mode = mfma_mode_probe(l4, l15);

    if (mode < 2) {
        int rw[4];
        #pragma unroll
        for (int v = 0; v < 4; v++) rw[v] = (mode == 0) ? (4 * l4 + v) : (l4 + 4 * v);
        int rbase = i0 + wv * 16;
        double a_reg[4][8];
        const double* arow = xtb + (size_t)(i0 + wv * 16 + l15) * C2q + l4;
        #pragma unroll
        for (int kc = 0; kc < 4; kc++)
            #pragma unroll
            for (int st = 0; st < 8; st++)
                a_reg[kc][st] = arow[kc * KC + 4 * st];
        double x2i[4];
        #pragma unroll
        for (int v = 0; v < 4; v++) x2i[v] = x2b[rbase + rw[v]];
        double best[4][KNN]; double mx[4];
        #pragma unroll
        for (int v = 0; v < 4; v++) {
            mx[v] = -DBL_MAX;
            #pragma unroll
            for (int k = 0; k < KNN; k++) best[v][k] = DBL_MAX;
        }
        {
            int j0 = jt_beg * T64;
            #pragma unroll
            for (int w = 0; w < 4; w++) {
                int idx = tid + w * 256; int r = idx >> 4, c = (idx & 15) * 2;
                *(double2*)&sBB[0][r][c] = *(const double2*)&xtb[(size_t)(j0 + r) * C2q + c];
            }
            if (tid < T64) sx2j[0][tid] = x2b[j0 + tid];
        }
        __syncthreads();
        int q = 0;
        for (int jt = jt_beg; jt < jt_end; jt++) {
            int j0 = jt * T64;
            d64x4 acc[4];
            #pragma unroll
            for (int bc = 0; bc < 4; bc++)
                #pragma unroll
                for (int v = 0; v < 4; v++) acc[bc][v] = 0.0;
            #pragma unroll
            for (int kc = 0; kc < 4; kc++) {
                const int cb = kc & 1, nb = cb ^ 1, nkc = (kc + 1) & 3;
                const bool lastk = (kc == 3);
                bool hn = !lastk || (jt + 1 < jt_end);
                int nj0 = lastk ? j0 + T64 : j0;
                double2 sreg[4]; double xr = 0.0;
                if (hn) {
                    #pragma unroll
                    for (int w = 0; w < 4; w++) {
                        int idx = tid + w * 256; int r = idx >> 4, c = (idx & 15) * 2;
                        sreg[w] = *(const double2*)&xtb[(size_t)(nj0 + r) * C2q + nkc * KC + c];
                    }
                    if (lastk && tid < T64) xr = x2b[nj0 + tid];
                }
                #pragma unroll
                for (int st = 0; st < 8; st++) {
                    double av = a_reg[kc][st];
                    #pragma unroll
                    for (int bc = 0; bc < 4; bc++) {
                        double bv = sBB[cb][bc * 16 + l15][4 * st + l4];
                        acc[bc] = __builtin_amdgcn_mfma_f64_16x16x4f64(av, bv, acc[bc], 0, 0, 0);
                    }
                }
                if (hn) {
                    #pragma unroll
                    for (int w = 0; w < 4; w++) {
                        int idx = tid + w * 256; int r = idx >> 4, c = (idx & 15) * 2;
                        *(double2*)&sBB[nb][r][c] = sreg[w];
                    }
                    if (lastk && tid < T64) sx2j[q ^ 1][tid] = xr;
                }
                __syncthreads();
            }
            #pragma unroll
            for (int bc = 0; bc < 4; bc++) {
                double xj = sx2j[q][bc * 16 + l15];
                #pragma unroll
                for (int v = 0; v < 4; v++) {
                    double d2 = x2i[v] + xj - 2.0 * acc[bc][v];
                    mx[v] = fmax(mx[v], d2);
                    ins5(best[v], d2);
                }
            }
            q ^= 1;
        }
        for (int m = 1; m <= 8; m <<= 1) {
            #pragma unroll
            for (int v = 0; v < 4; v++) {
                double p[KNN];
                #pragma unroll
                for (int k = 0; k < KNN; k++) p[k] = __shfl_xor(best[v][k], m);
                mx[v] = fmax(mx[v], __shfl_xor(mx[v], m));
                merge5(best[v], p);
            }
        }
        if (l15 == 0) {
            #pragma unroll
            for (int v = 0; v < 4; v++) {
                int gi = b * Nq + rbase + rw[v];
                size_t base = ((size_t)s * BNq + gi) * KNN;
                #pragma unroll
                for (int k = 0; k < KNN; k++) pbest[base + k] = best[v][k];
                pmax[(size_t)s * BNq + gi] = mx[v];
            }
        }
    } else {
        // ---------------- VALU fallback (v2.7 verbatim; sBB aliased) -------
        double (*sA)[LDP] = sBB[0];
        double (*sB)[LDP] = sBB[1];
        int tx = tid & 15, ty = tid >> 4;
        double x2i[4];
        #pragma unroll
        for (int r = 0; r < 4; r++) x2i[r] = x2b[i0 + ty + 16 * r];
        double best[4][KNN]; double mx[4];
        #pragma unroll
        for (int r = 0; r < 4; r++) {
            mx[r] = -DBL_MAX;
            #pragma unroll
            for (int k = 0; k < KNN; k++) best[r][k] = DBL_MAX;
        }
        for (int jt = jt_beg; jt < jt_end; jt++) {
            int j0 = jt * T64;
            double acc[4][4];
            #pragma unroll
            for (int r = 0; r < 4; r++)
                #pragma unroll
                for (int q = 0; q < 4; q++) acc[r][q] = 0.0;
            for (int kc = 0; kc < 4; kc++) {
                __syncthreads();
                #pragma unroll
                for (int idx = tid; idx < T64 * KC / 2; idx += 256) {
                    int r = idx >> 4, c = (idx & 15) * 2;
                    *(double2*)&sA[r][c] = *(const double2*)&xtb[(size_t)(i0 + r) * C2q + kc * KC + c];
                    *(double2*)&sB[r][c] = *(const double2*)&xtb[(size_t)(j0 + r) * C2q + kc * KC + c];
                }
                if (kc == 0 && tid < T64) sx2j[0][tid] = x2b[j0 + tid];
                __syncthreads();
                #pragma unroll 4
                for (int cc = 0; cc < KC; cc += 2) {
                    double2 xi[4], xj[4];
                    #pragma unroll
                    for (int r = 0; r < 4; r++) xi[r] = *(const double2*)&sA[ty + 16 * r][cc];
                    #pragma unroll
                    for (int q = 0; q < 4; q++) xj[q] = *(const double2*)&sB[tx + 16 * q][cc];
                    #pragma unroll
                    for (int r = 0; r < 4; r++)
                        #pragma unroll
                        for (int q = 0; q < 4; q++) acc[r][q] += xi[r].x * xj[q].x;
                    #pragma unroll
                    for (int r = 0; r < 4; r++)
                        #pragma unroll
                        for (int q = 0; q < 4; q++) acc[r][q] += xi[r].y * xj[q].y;
                }
            }
            #pragma unroll
            for (int r = 0; r < 4; r++)
                #pragma unroll
                for (int q = 0; q < 4; q++) {
                    double d2 = x2i[r] + sx2j[0][tx + 16 * q] - 2.0 * acc[r][q];
                    mx[r] = fmax(mx[r], d2);
                    ins5(best[r], d2);
                }
        }
        for (int m = 1; m <= 8; m <<= 1) {
            #pragma unroll
            for (int r = 0; r < 4; r++) {
                double p[KNN];
                #pragma unroll
                for (int k = 0; k < KNN; k++) p[k] = __shfl_xor(best[r][k], m);
                mx[r] = fmax(mx[r], __shfl_xor(mx[r], m));
                merge5(best[r], p);
            }
        }
        if (tx == 0) {
            #pragma unroll
            for (int r = 0; r < 4; r++) {
                int gi = b * Nq + i0 + ty + 16 * r;
                size_t base = ((size_t)s * BNq + gi) * KNN;
                #pragma unroll
                for (int k = 0; k < KNN; k++) pbest[base + k] = best[r][k];
                pmax[(size_t)s * BNq + gi] = mx[r];
            }
        }
    }
}

// merge pass1 partials -> density; fold per-batch max into maxd2 via atomic.
__global__ void ctm_merge1(const double* __restrict__ pbest, const double* __restrict__ pmax,
                           double* density, double* maxd2) {
    int t = blockIdx.x * blockDim.x + threadIdx.x;
    if (t >= BNq) return;
    double a[KNN];
    #pragma unroll
    for (int k = 0; k < KNN; k++) a[k] = pbest[(size_t)t * KNN + k];
    double mxv = pmax[t];
    #pragma unroll
    for (int s = 1; s < NSPL; s++) {
        double p[KNN];
        #pragma unroll
        for (int k = 0; k < KNN; k++) p[k] = pbest[((size_t)s * BNq + t) * KNN + k];
        merge5(a, p);
        mxv = fmax(mxv, pmax[(size_t)s * BNq + t]);
    }
    double sum = 0.0;
    #pragma unroll
    for (int k = 0; k < KNN; k++) sum += fmax(a[k], 0.0);
    density[t] = exp(-sum / (double)(C2q * KNN)) + (double)(tf_uniform(t) * 1e-6f);
    atomicMaxPosD(&maxd2[t / Nq], mxv);
}

// sort by density desc (idx asc ties) -> full rank permutation per batch.
__global__ __launch_bounds__(1024)
void ctm_sortd(const double* __restrict__ density, int* perm) {
    __shared__ double s[4096];
    __shared__ int   si[4096];
    int b = blockIdx.x, tid = threadIdx.x;
    for (int i = tid; i < 4096; i += 1024) {
        if (i < Nq) {
            double v = density[b * Nq + i];
            s[i] = isnan(v) ? -DBL_MAX : v;
            si[i] = i;
        } else { s[i] = -DBL_MAX; si[i] = 0x7fffffff; }
    }
    __syncthreads();
    for (int k = 2; k <= 4096; k <<= 1) {
        for (int j = k >> 1; j > 0; j >>= 1) {
            for (int i = tid; i < 4096; i += 1024) {
                int ixj = i ^ j;
                if (ixj > i) {
                    double s1 = s[i], s2 = s[ixj];
                    int i1 = si[i], i2 = si[ixj];
                    bool before_ij = (s1 > s2) || (s1 == s2 && i1 < i2);
                    bool before_ji = (s2 > s1) || (s2 == s1 && i2 < i1);
                    bool doswap = ((i & k) == 0) ? before_ji : before_ij;
                    if (doswap) { s[i] = s2; s[ixj] = s1; si[i] = i2; si[ixj] = i1; }
                }
            }
            __syncthreads();
        }
    }
    for (int t = tid; t < Nq; t += 1024) {
        int v = si[t];
        perm[b * Nq + t] = ((unsigned)v < (unsigned)Nq) ? v : 0;
    }
}

// init the u64-encoded running minima to enc(DBL_MAX)
__global__ void ctm_initmin(u64* pmin2u) {
    int t = blockIdx.x * blockDim.x + threadIdx.x;
    if (t < BNq) pmin2u[t] = ENC_DBL_MAX;
}

// pass2 TRIANGULAR: one lower-tri tile-pair (it,jt<=it) per block, in rank
// space, rows gathered through perm.  Mask inside tile = density[j] >
// density[i] (exact reference predicate).  Row minima fold via atomicMin on
// the ordered-u64 encoding (order-invariant fmin).
__global__ __launch_bounds__(256, 2)
void ctm_pass2t(const double* __restrict__ xt, const double* __restrict__ x2,
                const double* __restrict__ density, const int* __restrict__ perm,
                u64* pmin2u) {
    __shared__ double sBB[2][T64][LDP];
    __shared__ double sx2j[T64];
    __shared__ double sdj[T64];
    __shared__ int    sI[T64];
    __shared__ int    sJ[T64];
    __shared__ double sp[4][T64];
    int blk = blockIdx.x;
    int b = blk & (Bq - 1);
    int p = blk >> 2;                 // 0..NPAIR-1
    int it = (int)((sqrt(8.0 * (double)p + 1.0) - 1.0) * 0.5);
    while ((it + 1) * (it + 2) / 2 <= p) ++it;
    while (it * (it + 1) / 2 > p) --it;
    int jt = p - it * (it + 1) / 2;   // 0..it
    int i0 = it * T64, j0 = jt * T64;
    int tid = threadIdx.x;
    const double* xtb = xt + (size_t)b * Nq * C2q;
    const double* x2b = x2 + (size_t)b * Nq;
    const double* db  = density + (size_t)b * Nq;
    const int* pb = perm + b * Nq;
    if (tid < T64) sI[tid] = pb[i0 + tid];
    else if (tid < 2 * T64) sJ[tid - T64] = pb[j0 + tid - T64];
    __syncthreads();
    int wv = tid >> 6, ln = tid & 63;
    int l15 = ln & 15, l4 = ln >> 4;
    int mode = mfma_mode_probe(l4, l15);

    if (mode < 2) {
        int rw[4];
        #pragma unroll
        for (int v = 0; v < 4; v++) rw[v] = (mode == 0) ? (4 * l4 + v) : (l4 + 4 * v);
        int rloc = wv * 16;
        double a_reg[4][8];
        const double* arow = xtb + (size_t)sI[rloc + l15] * C2q + l4;
        #pragma unroll
        for (int kc = 0; kc < 4; kc++)
            #pragma unroll
            for (int st = 0; st < 8; st++)
                a_reg[kc][st] = arow[kc * KC + 4 * st];
        double x2i[4], di[4];
        #pragma unroll
        for (int v = 0; v < 4; v++) {
            int o = sI[rloc + rw[v]];
            x2i[v] = x2b[o];
            di[v]  = db[o];
        }
        // stage B kc=0 + x2/density (gathered)
        #pragma unroll
        for (int w = 0; w < 4; w++) {
            int idx = tid + w * 256; int r = idx >> 4, c = (idx & 15) * 2;
            *(double2*)&sBB[0][r][c] = *(const double2*)&xtb[(size_t)sJ[r] * C2q + c];
        }
        if (tid < T64) { int o = sJ[tid]; sx2j[tid] = x2b[o]; sdj[tid] = db[o]; }
        __syncthreads();
        d64x4 acc[4];
        #pragma unroll
        for (int bc = 0; bc < 4; bc++)
            #pragma unroll
            for (int v = 0; v < 4; v++) acc[bc][v] = 0.0;
        #pragma unroll
        for (int kc = 0; kc < 4; kc++) {
            const int cb = kc & 1, nb = cb ^ 1;
            const bool hn = (kc < 3);
            double2 sreg[4];
            if (hn) {
                #pragma unroll
                for (int w = 0; w < 4; w++) {
                    int idx = tid + w * 256; int r = idx >> 4, c = (idx & 15) * 2;
                    sreg[w] = *(const double2*)&xtb[(size_t)sJ[r] * C2q + (kc + 1) * KC + c];
                }
            }
            #pragma unroll
            for (int st = 0; st < 8; st++) {
                double av = a_reg[kc][st];
                #pragma unroll
                for (int bc = 0; bc < 4; bc++) {
                    double bv = sBB[cb][bc * 16 + l15][4 * st + l4];
                    acc[bc] = __builtin_amdgcn_mfma_f64_16x16x4f64(av, bv, acc[bc], 0, 0, 0);
                }
            }
            if (hn) {
                #pragma unroll
                for (int w = 0; w < 4; w++) {
                    int idx = tid + w * 256; int r = idx >> 4, c = (idx & 15) * 2;
                    *(double2*)&sBB[nb][r][c] = sreg[w];
                }
            }
            __syncthreads();
        }
        double mn[4];
        #pragma unroll
        for (int v = 0; v < 4; v++) mn[v] = DBL_MAX;
        #pragma unroll
        for (int bc = 0; bc < 4; bc++) {
            double xj = sx2j[bc * 16 + l15];
            double dj = sdj[bc * 16 + l15];
            #pragma unroll
            for (int v = 0; v < 4; v++) {
                double d2 = x2i[v] + xj - 2.0 * acc[bc][v];
                if (dj > di[v]) mn[v] = fmin(mn[v], d2);
            }
        }
        for (int m = 1; m <= 8; m <<= 1) {
            #pragma unroll
            for (int v = 0; v < 4; v++) mn[v] = fmin(mn[v], __shfl_xor(mn[v], m));
        }
        if (l15 == 0) {
            #pragma unroll
            for (int v = 0; v < 4; v++)
                if (mn[v] < DBL_MAX)
                    atomicMin(&pmin2u[b * Nq + i0 + rloc + rw[v]], encD(mn[v]));
        }
    } else {
        // scalar insurance path (never taken on validated HW)
        int rl = tid & 63;
        int cg = tid >> 6;
        int ro = sI[rl];
        double x2i = x2b[ro];
        double di = db[ro];
        const double* xr = xtb + (size_t)ro * C2q;
        double mn = DBL_MAX;
        for (int cc = 0; cc < 16; cc++) {
            int co = sJ[cg * 16 + cc];
            if (db[co] > di) {
                const double* xc = xtb + (size_t)co * C2q;
                double dot = 0.0;
                for (int k = 0; k < C2q; k++) dot += xr[k] * xc[k];
                mn = fmin(mn, x2i + x2b[co] - 2.0 * dot);
            }
        }
        sp[cg][rl] = mn;
        __syncthreads();
        if (cg == 0) {
            mn = fmin(fmin(sp[0][rl], sp[1][rl]), fmin(sp[2][rl], sp[3][rl]));
            if (mn < DBL_MAX)
                atomicMin(&pmin2u[b * Nq + i0 + rl], encD(mn));
        }
    }
}

// merge triangular minima -> score (scatter through perm)
__global__ void ctm_merge2t(const u64* __restrict__ pmin2u, const double* __restrict__ maxd2,
                            const double* __restrict__ density, const int* __restrict__ perm,
                            double* score) {
    int t = blockIdx.x * blockDim.x + threadIdx.x;
    if (t >= BNq) return;
    int b = t / Nq;
    double m = decD(pmin2u[t]);
    double mm = fmin(maxd2[b], m);
    int orig = b * Nq + perm[t];
    score[orig] = sqrt(fmax(mm, 0.0)) / sqrt((double)C2q) * density[orig];
}

// top-784 with jax.lax.top_k semantics: total order (score desc, idx asc).
__global__ __launch_bounds__(1024)
void ctm_sort(const double* __restrict__ score, int* index_down) {
    __shared__ double s[4096];
    __shared__ int   si[4096];
    int b = blockIdx.x, tid = threadIdx.x;
    for (int i = tid; i < 4096; i += 1024) {
        if (i < Nq) {
            double v = score[b * Nq + i];
            s[i] = isnan(v) ? -DBL_MAX : v;
            si[i] = i;
        } else { s[i] = -DBL_MAX; si[i] = 0x7fffffff; }
    }
    __syncthreads();
    for (int k = 2; k <= 4096; k <<= 1) {
        for (int j = k >> 1; j > 0; j >>= 1) {
            for (int i = tid; i < 4096; i += 1024) {
                int ixj = i ^ j;
                if (ixj > i) {
                    double s1 = s[i], s2 = s[ixj];
                    int i1 = si[i], i2 = si[ixj];
                    bool before_ij = (s1 > s2) || (s1 == s2 && i1 < i2);
                    bool before_ji = (s2 > s1) || (s2 == s1 && i2 < i1);
                    bool doswap = ((i & k) == 0) ? before_ji : before_ij;
                    if (doswap) { s[i] = s2; s[ixj] = s1; si[i] = i2; si[ixj] = i1; }
                }
            }
            __syncthreads();
        }
    }
    for (int t = tid; t < NSq; t += 1024) {
        int v = si[t];
        index_down[b * NSq + t] = ((unsigned)v < (unsigned)Nq) ? v : 0;
    }
}

// assign: argmin over centers (lexicographic (d,sc) min), split x2.
__global__ __launch_bounds__(256, 2)
void ctm_assign(const double* __restrict__ xt, const double* __restrict__ x2,
                const int* __restrict__ index_down, double* pbd, int* pbs) {
    __shared__ double sBB[2][T64][LDP];
    __shared__ double sx2c[T64];
    __shared__ int    sidx[T64];
    int blk = blockIdx.x;
    int b  = blk & (Bq - 1);
    int s  = (blk >> 2) & (NSPA - 1);
    int it = blk >> 3;
    int tid = threadIdx.x;
    const double* xtb = xt + (size_t)b * Nq * C2q;
    const double* x2b = x2 + (size_t)b * Nq;
    int i0 = it * T64;
    int jt_beg = c_spla[s], jt_end = c_spla[s + 1];

    int wv = tid >> 6, ln = tid & 63;
    int l15 = ln & 15, l4 = ln >> 4;
    int mode = mfma_mode_probe(l4, l15);

    if (mode < 2) {
        int rw[4];
        #pragma unroll
        for (int v = 0; v < 4; v++) rw[v] = (mode == 0) ? (4 * l4 + v) : (l4 + 4 * v);
        int rbase = i0 + wv * 16;
        double a_reg[4][8];
        const double* arow = xtb + (size_t)(i0 + wv * 16 + l15) * C2q + l4;
        #pragma unroll
        for (int kc = 0; kc < 4; kc++)
            #pragma unroll
            for (int st = 0; st < 8; st++)
                a_reg[kc][st] = arow[kc * KC + 4 * st];
        double x2i[4], bd[4];
        int bs[4];
        #pragma unroll
        for (int v = 0; v < 4; v++) { x2i[v] = x2b[rbase + rw[v]]; bd[v] = DBL_MAX; bs[v] = NSq - 1; }
        for (int jt = jt_beg; jt < jt_end; jt++) {
            int j0 = jt * T64;
            __syncthreads();
            if (tid < T64) {
                int j = index_down[b * NSq + min(j0 + tid, NSq - 1)];
                sidx[tid] = j;
                sx2c[tid] = x2b[j];
            }
            __syncthreads();
            d64x4 acc[4];
            #pragma unroll
            for (int bc = 0; bc < 4; bc++)
                #pragma unroll
                for (int v = 0; v < 4; v++) acc[bc][v] = 0.0;
            for (int kc = 0; kc < 4; kc++) {
                if (kc) __syncthreads();
                #pragma unroll
                for (int idx = tid; idx < T64 * KC / 2; idx += 256) {
                    int r = idx >> 4, c = (idx & 15) * 2;
                    *(double2*)&sBB[0][r][c] = *(const double2*)&xtb[(size_t)sidx[r] * C2q + kc * KC + c];
                }
                __syncthreads();
                #pragma unroll
                for (int st = 0; st < 8; st++) {
                    double av = a_reg[kc][st];
                    #pragma unroll
                    for (int bc = 0; bc < 4; bc++) {
                        double bv = sBB[0][bc * 16 + l15][4 * st + l4];
                        acc[bc] = __builtin_amdgcn_mfma_f64_16x16x4f64(av, bv, acc[bc], 0, 0, 0);
                    }
                }
            }
            #pragma unroll
            for (int bc = 0; bc < 4; bc++) {
                int sc = j0 + bc * 16 + l15;
                double xc = sx2c[bc * 16 + l15];
                #pragma unroll
                for (int v = 0; v < 4; v++) {
                    double d = fmax(x2i[v] + xc - 2.0 * acc[bc][v], 0.0);
                    if (sc < NSq && (d < bd[v] || (d == bd[v] && sc < bs[v]))) { bd[v] = d; bs[v] = sc; }
                }
            }
        }
        for (int m = 1; m <= 8; m <<= 1) {
            #pragma unroll
            for (int v = 0; v < 4; v++) {
                double pd = __shfl_xor(bd[v], m);
                int    ps = __shfl_xor(bs[v], m);
                if (pd < bd[v] || (pd == bd[v] && ps < bs[v])) { bd[v] = pd; bs[v] = ps; }
            }
        }
        if (l15 == 0) {
            #pragma unroll
            for (int v = 0; v < 4; v++) {
                int gi = b * Nq + rbase + rw[v];
                pbd[(size_t)s * BNq + gi] = bd[v];
                pbs[(size_t)s * BNq + gi] = bs[v];
            }
        }
    } else {
        double (*sA)[LDP] = sBB[0];
        double (*sB)[LDP] = sBB[1];
        int tx = tid & 15, ty = tid >> 4;
        double x2i[4], bd[4];
        int bs[4];
        #pragma unroll
        for (int r = 0; r < 4; r++) { x2i[r] = x2b[i0 + ty + 16 * r]; bd[r] = DBL_MAX; bs[r] = NSq - 1; }
        for (int jt = jt_beg; jt < jt_end; jt++) {
            int j0 = jt * T64;
            __syncthreads();
            if (tid < T64) {
                int j = index_down[b * NSq + min(j0 + tid, NSq - 1)];
                sidx[tid] = j;
                sx2c[tid] = x2b[j];
            }
            __syncthreads();
            double acc[4][4];
            #pragma unroll
            for (int r = 0; r < 4; r++)
                #pragma unroll
                for (int q = 0; q < 4; q++) acc[r][q] = 0.0;
            for (int kc = 0; kc < 4; kc++) {
                if (kc) __syncthreads();
                #pragma unroll
                for (int idx = tid; idx < T64 * KC / 2; idx += 256) {
                    int r = idx >> 4, c = (idx & 15) * 2;
                    *(double2*)&sA[r][c] = *(const double2*)&xtb[(size_t)(i0 + r) * C2q + kc * KC + c];
                    *(double2*)&sB[r][c] = *(const double2*)&xtb[(size_t)sidx[r] * C2q + kc * KC + c];
                }
                __syncthreads();
                #pragma unroll 4
                for (int cc = 0; cc < KC; cc += 2) {
                    double2 xi[4], xj[4];
                    #pragma unroll
                    for (int r = 0; r < 4; r++) xi[r] = *(const double2*)&sA[ty + 16 * r][cc];
                    #pragma unroll
                    for (int q = 0; q < 4; q++) xj[q] = *(const double2*)&sB[tx + 16 * q][cc];
                    #pragma unroll
                    for (int r = 0; r < 4; r++)
                        #pragma unroll
                        for (int q = 0; q < 4; q++) acc[r][q] += xi[r].x * xj[q].x;
                    #pragma unroll
                    for (int r = 0; r < 4; r++)
                        #pragma unroll
                        for (int q = 0; q < 4; q++) acc[r][q] += xi[r].y * xj[q].y;
                }
            }
            #pragma unroll
            for (int r = 0; r < 4; r++)
                #pragma unroll
                for (int q = 0; q < 4; q++) {
                    int sc = j0 + tx + 16 * q;
                    double d = fmax(x2i[r] + sx2c[tx + 16 * q] - 2.0 * acc[r][q], 0.0);
                    if (sc < NSq && (d < bd[r] || (d == bd[r] && sc < bs[r]))) { bd[r] = d; bs[r] = sc; }
                }
        }
        for (int m = 1; m <= 8; m <<= 1) {
            #pragma unroll
            for (int r = 0; r < 4; r++) {
                double pd = __shfl_xor(bd[r], m);
                int    ps = __shfl_xor(bs[r], m);
                if (pd < bd[r] || (pd == bd[r] && ps < bs[r])) { bd[r] = pd; bs[r] = ps; }
            }
        }
        if (tx == 0) {
            #pragma unroll
            for (int r = 0; r < 4; r++) {
                int gi = b * Nq + i0 + ty + 16 * r;
                pbd[(size_t)s * BNq + gi] = bd[r];
                pbs[(size_t)s * BNq + gi] = bs[r];
            }
        }
    }
}

// merge assign partials (lexicographic (d,sc) min == first-min semantics)
__global__ void ctm_merge3(const double* __restrict__ pbd, const int* __restrict__ pbs,
                           int* idx_cluster) {
    int t = blockIdx.x * blockDim.x + threadIdx.x;
    if (t >= BNq) return;
    double d0 = pbd[t];          int s0 = pbs[t];
    double d1 = pbd[BNq + t];    int s1 = pbs[BNq + t];
    bool take1 = (d1 < d0) || (d1 == d0 && s1 < s0);
    idx_cluster[t] = take1 ? s1 : s0;
}

__global__ void ctm_override(const int* __restrict__ index_down, int* idx_cluster) {
    int t = blockIdx.x * blockDim.x + threadIdx.x;
    if (t >= Bq * NSq) return;
    int b = t / NSq, sc = t - b * NSq;
    int j = index_down[t];
    if ((unsigned)j < (unsigned)Nq) idx_cluster[b * Nq + j] = sc;
}

__global__ void ctm_zeromerged(double* xmerged) {
    int t = blockIdx.x * blockDim.x + threadIdx.x;
    if (t < Bq * NSq * C2q) xmerged[t] = 0.0;
}

__global__ void ctm_merge_w(const int* __restrict__ idx_cluster, const double* __restrict__ weightv,
                            double* allwc) {
    int t = blockIdx.x * blockDim.x + threadIdx.x;
    if (t >= BNq) return;
    int b = t / Nq;
    int sc = min(max(idx_cluster[t], 0), NSq - 1);
    atomicAdd(&allwc[b * NSq + sc], weightv[t]);
}

// merge_x, (point,channel)-parallel: one coalesced atomic per thread.
__global__ void ctm_merge_x(const int* __restrict__ idx_cluster, const double* __restrict__ weightv,
                            const double* __restrict__ allwc, const double* __restrict__ xt,
                            double* nw, double* xmerged) {
    int id = blockIdx.x * blockDim.x + threadIdx.x;
    if (id >= BNq * C2q) return;
    int t = id / C2q, c = id - t * C2q;
    int b = t / Nq;
    int sc = min(max(idx_cluster[t], 0), NSq - 1);
    double nv = weightv[t] / (allwc[b * NSq + sc] + 1e-6);
    if (c == 0) nw[t] = nv;
    atomicAdd(&xmerged[((size_t)(b * NSq + sc)) * C2q + c], xt[(size_t)t * C2q + c] * nv);
}

__global__ void ctm_out0(const double* __restrict__ xmerged, float* out) {
    int t = blockIdx.x * blockDim.x + threadIdx.x;
    if (t >= Bq * NSq * C2q) return;
    out[t] = (float)xmerged[t];
}

__global__ void ctm_out12(const int* __restrict__ idx_agg, const int* __restrict__ idx_cluster,
                          const double* __restrict__ nw, const float* __restrict__ aggw,
                          float* out1, double* awd, double* maxawd) {
    int t = blockIdx.x * blockDim.x + threadIdx.x;
    if (t >= BNq) return;
    int b = t / Nq;
    int tok = clampTok(idx_agg[t]);
    int sc = idx_cluster[b * Nq + tok];
    out1[t] = (float)sc;
    double a = (double)aggw[t] * nw[b * Nq + tok];
    awd[t] = a;
    atomicMaxPosD(&maxawd[b], a);
}

__global__ void ctm_out2(const double* __restrict__ awd, const double* __restrict__ maxawd, float* out2) {
    int t = blockIdx.x * blockDim.x + threadIdx.x;
    if (t >= BNq) return;
    int b = t / Nq;
    out2[t] = (float)(awd[t] / maxawd[b]);
}

// ---------------------------------------------------------------------------
extern "C" void kernel_launch(void* const* d_in, const int* in_sizes, int n_in,
                              void* d_out, int out_size, void* d_ws, size_t ws_size,
                              hipStream_t stream) {
    const float* x     = (const float*)d_in[0];
    const float* loc   = (const float*)d_in[1];
    const int*   idxag = (const int*)  d_in[2];
    const float* aggw  = (const float*)d_in[3];
    const float* convw = (const float*)d_in[4];
    const float* convb = (const float*)d_in[5];
    const float* skipw = (const float*)d_in[6];
    const float* lng   = (const float*)d_in[7];
    const float* lnb   = (const float*)d_in[8];
    const float* confw = (const float*)d_in[9];
    const float* confb = (const float*)d_in[10];
    (void)in_sizes; (void)n_in;

    char* w = (char*)d_ws;
    size_t off = 0;
    auto alloc = [&](size_t bytes) -> void* {
        void* p = w + off; off = (off + bytes + 255) & ~(size_t)255; return p;
    };

    // ---- zero-initialized region (one memset) ----
    int*    cnt56   = (int*)   alloc((size_t)BNq * 4);
    double* allwtok = (double*)alloc((size_t)BNq * 8);
    double* xt      = (double*)alloc((size_t)BNq * C2q * 8);
    double* arena   = (double*)alloc((size_t)Bq * HWq * Cq * 8);   // xmap56T, later xmerged
    double* allwc   = (double*)alloc((size_t)Bq * NSq * 8);
    double* maxawd  = (double*)alloc((size_t)Bq * 8);
    double* maxd2   = (double*)alloc((size_t)Bq * 8);              // atomic max (init 0)
    size_t zero_bytes = off;
    // ---- non-zero region ----
    int*    cell56   = (int*)   alloc((size_t)BNq * 4);
    int*    cell28   = (int*)   alloc((size_t)BNq * 4);
    double* xmap28T  = (double*)alloc((size_t)Bq * HWOq * C2q * 8);
    float*  wT       = (float*) alloc((size_t)C2q * Cq * 9 * 4);
    double* x2       = (double*)alloc((size_t)BNq * 8);
    double* density  = (double*)alloc((size_t)BNq * 8);
    double* score    = (double*)alloc((size_t)BNq * 8);
    int*    indexdn  = (int*)   alloc((size_t)Bq * NSq * 4);
    int*    idxclu   = (int*)   alloc((size_t)BNq * 4);
    double* nw       = (double*)alloc((size_t)BNq * 8);
    double* weightv  = (double*)alloc((size_t)BNq * 8);
    double* awd      = (double*)alloc((size_t)BNq * 8);
    double* pbest    = (double*)alloc((size_t)NSPL * BNq * KNN * 8);  // 4.01 MB
    double* pmax     = (double*)alloc((size_t)NSPL * BNq * 8);
    double* pbd      = (double*)alloc((size_t)NSPA * BNq * 8);
    int*    pbs      = (int*)   alloc((size_t)NSPA * BNq * 4);
    size_t required = off;

    // perm + pmin2u ALIAS the pbest buffer (dead after ctm_merge1, stream
    // ordered): perm at +0 (50 KB), pmin2u at +128 KB (100 KB).  Zero extra ws.
    int* perm   = (int*)pbest;
    u64* pmin2u = (u64*)((char*)pbest + 131072);

    const int tb = 256;
    float* out = (float*)d_out;

    if (ws_size < required) {
        ctm_fallback<<<(out_size + tb - 1) / tb, tb, 0, stream>>>(out, out_size);
        return;
    }

    double* xmap56T = arena;
    double* xmerged = arena;   // reused after conv; re-zeroed below

    hipMemsetAsync(d_ws, 0, zero_bytes, stream);

    ctm_prep<<<(BNq + tb - 1) / tb, tb, 0, stream>>>(loc, idxag, aggw, cell56, cell28, cnt56, allwtok);
    ctm_wt<<<((C2q * Cq * 9) + tb - 1) / tb, tb, 0, stream>>>(convw, wT);
    ctm_t2m<<<((BNq * Cq) + tb - 1) / tb, tb, 0, stream>>>(x, idxag, cell56, cnt56, xmap56T);
    ctm_conv<<<Bq * (HWOq / 2), 256, 0, stream>>>(xmap56T, wT, convb, xmap28T);
    ctm_m2t<<<((BNq * C2q) + tb - 1) / tb, tb, 0, stream>>>(xmap28T, aggw, idxag, cell28, allwtok, xt);
    ctm_finalize<<<BNq, C2q, 0, stream>>>(xt, x, skipw, lng, lnb, confw, confb, x2, weightv);
    ctm_pass1<<<Bq * NSPL * NIT64, 256, 0, stream>>>(xt, x2, pbest, pmax);
    ctm_merge1<<<(BNq + tb - 1) / tb, tb, 0, stream>>>(pbest, pmax, density, maxd2);
    // pbest is dead from here; perm/pmin2u may overwrite it.
    ctm_sortd<<<Bq, 1024, 0, stream>>>(density, perm);
    ctm_initmin<<<(BNq + tb - 1) / tb, tb, 0, stream>>>(pmin2u);
    ctm_pass2t<<<Bq * NPAIR, 256, 0, stream>>>(xt, x2, density, perm, pmin2u);
    ctm_merge2t<<<(BNq + tb - 1) / tb, tb, 0, stream>>>(pmin2u, maxd2, density, perm, score);
    ctm_sort<<<Bq, 1024, 0, stream>>>(score, indexdn);
    ctm_assign<<<Bq * NSPA * NIT64, 256, 0, stream>>>(xt, x2, indexdn, pbd, pbs);
    ctm_merge3<<<(BNq + tb - 1) / tb, tb, 0, stream>>>(pbd, pbs, idxclu);
    ctm_override<<<((Bq * NSq) + tb - 1) / tb, tb, 0, stream>>>(indexdn, idxclu);
    ctm_zeromerged<<<((Bq * NSq * C2q) + tb - 1) / tb, tb, 0, stream>>>(xmerged);
    ctm_merge_w<<<(BNq + tb - 1) / tb, tb, 0, stream>>>(idxclu, weightv, allwc);
    ctm_merge_x<<<((BNq * C2q) + tb - 1) / tb, tb, 0, stream>>>(idxclu, weightv, allwc, xt, nw, xmerged);

    ctm_out0<<<((Bq * NSq * C2q) + tb - 1) / tb, tb, 0, stream>>>(xmerged, out);
    ctm_out12<<<(BNq + tb - 1) / tb, tb, 0, stream>>>(idxag, idxclu, nw, aggw,
                                                      out + (size_t)Bq * NSq * C2q, awd, maxawd);
    ctm_out2<<<(BNq + tb - 1) / tb, tb, 0, stream>>>(awd, maxawd,
                                                     out + (size_t)Bq * NSq * C2q + BNq);
}